// Round 6
// baseline (834.730 us; speedup 1.0000x reference)
//
#include <hip/hip_runtime.h>
#include <hip/hip_bf16.h>

#define BB 16
#define TTc 256
#define SS 2048
#define DD 512
#define II 1024
#define LL 4
#define MAXPOSc 4096
#define CT 16   // tokens per conv block

typedef __bf16 bf8_t __attribute__((ext_vector_type(8)));
typedef __bf16 bf4_t __attribute__((ext_vector_type(4)));
typedef float  f4_t  __attribute__((ext_vector_type(4)));

__device__ __forceinline__ void async_ld16(const __bf16* g, __bf16* lds)
{
    __builtin_amdgcn_global_load_lds(
        (const __attribute__((address_space(1))) void*)g,
        (__attribute__((address_space(3))) void*)lds,
        16, 0, 0);
}

// tanh-approx GELU: 0.5 v (1 + tanh(0.7978845608 (v + 0.044715 v^3)))
__device__ __forceinline__ float gelu_f(float v)
{
    float u = 0.7978845608f * v * (1.0f + 0.044715f * v * v);
    float e = __expf(2.0f * u);
    float t = 1.0f - 2.0f * __builtin_amdgcn_rcpf(e + 1.0f);
    return 0.5f * v * (1.0f + t);
}

// ---------------- weight transpose + cast: (L,R,C) f32 -> (L,C,R) bf16 ----------------
__global__ void transpose_bf16_kernel(const float* __restrict__ in, __bf16* __restrict__ out,
                                      int R, int C)
{
    long idx = (long)blockIdx.x * 256 + threadIdx.x;
    long RC = (long)R * C;
    long total = RC * LL;
    if (idx >= total) return;
    int m = (int)(idx / RC);
    long rem = idx - (long)m * RC;
    int c = (int)(rem / R);
    int r = (int)(rem - (long)c * R);
    out[idx] = (__bf16)in[(long)m * RC + (long)r * C + c];
}

// ---------------- GRN flag: any(grn_g != 0 || grn_b != 0) per layer ----------------
__global__ __launch_bounds__(256) void grn_flag_kernel(const float* __restrict__ gg,
                                                       const float* __restrict__ gb,
                                                       int* __restrict__ flag)
{
    int l = blockIdx.x;
    __shared__ int any_s;
    if (threadIdx.x == 0) any_s = 0;
    __syncthreads();
    int a = 0;
    for (int i = threadIdx.x; i < II; i += 256)
        a |= (gg[l * II + i] != 0.f) | (gb[l * II + i] != 0.f);
    if (a) atomicOr(&any_s, 1);
    __syncthreads();
    if (threadIdx.x == 0) flag[l] = any_s;
}

// ---------------- embedding + rope-add + mask ----------------
__global__ __launch_bounds__(128) void embed_kernel(const int* __restrict__ text,
                                                    const float* __restrict__ table,
                                                    const float* __restrict__ freq,
                                                    float* __restrict__ x,
                                                    float* __restrict__ keepf)
{
    int m = blockIdx.x;
    int b = m >> 11;          // S = 2048
    int t = m & (SS - 1);
    int tp = 0;
    if (t < TTc) tp = text[b * TTc + t] + 1;
    if (threadIdx.x == 0) keepf[m] = (tp != 0) ? 1.f : 0.f;
    int d = threadIdx.x * 4;
    f4_t o = {0.f, 0.f, 0.f, 0.f};
    if (tp != 0) {
        f4_t e = *reinterpret_cast<const f4_t*>(&table[(size_t)tp * DD + d]);
        f4_t f = *reinterpret_cast<const f4_t*>(&freq[(size_t)t * DD + d]);
        o = e + f;
    }
    *reinterpret_cast<f4_t*>(&x[(size_t)m * DD + d]) = o;
}

// ---------------- per-batch counts + valid-position compaction ----------------
__global__ __launch_bounds__(256) void counts_kernel(const float* __restrict__ keepf,
                                                     const int* __restrict__ audio,
                                                     int* __restrict__ counts,
                                                     int* __restrict__ vpos)
{
    int b = blockIdx.x, tid = threadIdx.x;
    int mask8 = 0, cnt = 0;
#pragma unroll
    for (int j = 0; j < 8; ++j) {
        int t = tid * 8 + j;
        int k = keepf[b * SS + t] != 0.f;
        mask8 |= k << j;
        cnt += k;
    }
    __shared__ int sc[256];
    sc[tid] = cnt;
    __syncthreads();
    for (int off = 1; off < 256; off <<= 1) {
        int v = sc[tid];
        int add = (tid >= off) ? sc[tid - off] : 0;
        __syncthreads();
        sc[tid] = v + add;
        __syncthreads();
    }
    int incl = sc[tid];
    int Vn = sc[255];
    int r = incl - cnt;
#pragma unroll
    for (int j = 0; j < 8; ++j)
        if (mask8 & (1 << j)) vpos[b * SS + (r++)] = tid * 8 + j;
    int ac = 0;
#pragma unroll
    for (int j = 0; j < 8; ++j) ac += (audio[b * SS + tid * 8 + j] != 0);
    __syncthreads();
    sc[tid] = ac;
    __syncthreads();
    for (int off = 128; off > 0; off >>= 1) {
        if (tid < off) sc[tid] += sc[tid + off];
        __syncthreads();
    }
    if (tid == 0) { counts[2 * b] = sc[0]; counts[2 * b + 1] = Vn; }
}

// ---------------- depthwise conv(7) + layernorm -> bf16 (LDS-tiled, 16 tok/block) ----------------
__global__ __launch_bounds__(256) void conv_ln_kernel(const float* __restrict__ x,
                                                      const float* __restrict__ w,
                                                      const float* __restrict__ wb,
                                                      const float* __restrict__ g,
                                                      const float* __restrict__ bta,
                                                      __bf16* __restrict__ hn)
{
    __shared__ float xs[CT + 6][DD];   // 44 KB
    int blk = blockIdx.x;
    int b = blk >> 7;                  // SS/CT = 128 blocks per batch
    int t0 = (blk & 127) * CT;
    int tid = threadIdx.x;
    const float* xb = x + (size_t)b * SS * DD;
#pragma unroll
    for (int it = 0; it < (CT + 6) * (DD / 4) / 256; ++it) {
        int i = it * 256 + tid;
        int ri = i >> 7;               // DD/4 = 128
        int c4 = i & 127;
        int tr = t0 - 3 + ri;
        f4_t v = {0.f, 0.f, 0.f, 0.f};
        if (tr >= 0 && tr < SS) v = *reinterpret_cast<const f4_t*>(&xb[(size_t)tr * DD + c4 * 4]);
        *reinterpret_cast<f4_t*>(&xs[ri][c4 * 4]) = v;
    }
    __syncthreads();
    int tt = tid >> 4;                 // token within tile 0..15
    int lg = tid & 15;
    float hv[32];
    float s = 0.f, s2 = 0.f;
#pragma unroll
    for (int j = 0; j < 8; ++j) {
        int c = lg * 4 + j * 64;
        float a0 = wb[c], a1 = wb[c + 1], a2 = wb[c + 2], a3 = wb[c + 3];
#pragma unroll
        for (int k = 0; k < 7; ++k) {
            f4_t xv = *reinterpret_cast<const f4_t*>(&xs[tt + k][c]);
            a0 += xv[0] * w[(c + 0) * 7 + k];
            a1 += xv[1] * w[(c + 1) * 7 + k];
            a2 += xv[2] * w[(c + 2) * 7 + k];
            a3 += xv[3] * w[(c + 3) * 7 + k];
        }
        hv[j * 4 + 0] = a0; hv[j * 4 + 1] = a1; hv[j * 4 + 2] = a2; hv[j * 4 + 3] = a3;
        s += a0 + a1 + a2 + a3;
        s2 += a0 * a0 + a1 * a1 + a2 * a2 + a3 * a3;
    }
#pragma unroll
    for (int off = 8; off > 0; off >>= 1) {
        s  += __shfl_down(s, off, 16);
        s2 += __shfl_down(s2, off, 16);
    }
    s  = __shfl(s, 0, 16);
    s2 = __shfl(s2, 0, 16);
    float mu = s / DD;
    float rstd = rsqrtf(s2 / DD - mu * mu + 1e-6f);
    __bf16* hr = hn + ((size_t)b * SS + t0 + tt) * DD;
#pragma unroll
    for (int j = 0; j < 8; ++j) {
        int c = lg * 4 + j * 64;
        bf4_t o;
#pragma unroll
        for (int q = 0; q < 4; ++q)
            o[q] = (__bf16)((hv[j * 4 + q] - mu) * rstd * g[c + q] + bta[c + q]);
        *reinterpret_cast<bf4_t*>(&hr[c]) = o;
    }
}

// ---------------- bf16 MFMA GEMM: C[M,N] = A[M,K] x Wt[N,K]^T ----------------
// BK=32 (R3's high-occupancy profile: 16.9 KB LDS arena, low VGPR) + XOR bank
// swizzle (R5-verified: conflicts -> 0): row's global 16B-chunk g lives at LDS
// slot g ^ (row&3); staging DMA dest stays wave-uniform + lane*16, only each
// lane's GLOBAL source chunk is permuted. Fragment read offset (quad^(fr&3))*8.
// XCD swizzle for L2 locality. Epilogue: LDS-transpose -> coalesced stores.
// EPI 0: out_bf16 = gelu(acc + bias)                 (GEMM1)
// EPI 1: out_f32  = (acc + bias + res) * keep[m]     (GEMM2, in-place residual)
template <int EPI>
__global__ __launch_bounds__(256) void gemm_kernel(const __bf16* __restrict__ A,
                                                   const __bf16* __restrict__ Wt,
                                                   int K, int N, int nlog,
                                                   const float* __restrict__ bias,
                                                   __bf16* __restrict__ outb,
                                                   float* __restrict__ outf,
                                                   const float* __restrict__ res,
                                                   const float* __restrict__ keep)
{
    __shared__ float smem[4224];               // 16.9 KB arena
    __bf16* As = (__bf16*)smem;                // 128x32 bf16 = 8 KB
    __bf16* Bs = As + 128 * 32;                // 8 KB
    float*  cs = smem;                         // epilogue 32x132 f32

    int tid = threadIdx.x;
    int lane = tid & 63, wid = tid >> 6;

    // XCD-aware swizzle: consecutive slots within an XCD share the M-tile.
    int idx = blockIdx.x;
    int xcd = idx & 7;
    int s = idx >> 3;
    int n_t = s & ((1 << nlog) - 1);
    int m_t = ((s >> nlog) << 3) | xcd;
    int n0 = n_t * 128, m0 = m_t * 128;

    f4_t acc[4][4];
#pragma unroll
    for (int i = 0; i < 4; ++i)
#pragma unroll
        for (int j = 0; j < 4; ++j) { f4_t z = {0.f, 0.f, 0.f, 0.f}; acc[i][j] = z; }

    const int wm = (wid >> 1) * 64, wn = (wid & 1) * 64;
    int fr = lane & 15, quad = lane >> 4;

    // staging: lane's LDS chunk = (row = 16-blk + (lane>>2), slot = lane&3);
    // its global source chunk is slot ^ (row&3) = (lane&3) ^ ((lane>>2)&3).
    int r4 = lane >> 2;
    int gch = (lane & 3) ^ (r4 & 3);
    int srow = wid * 32 + r4;
    const __bf16* ag = &A[(size_t)(m0 + srow) * K + gch * 8];
    const __bf16* bg = &Wt[(size_t)(n0 + srow) * K + gch * 8];
    __bf16* al0 = &As[(wid * 32) * 32];
    __bf16* al1 = &As[(wid * 32 + 16) * 32];
    __bf16* bl0 = &Bs[(wid * 32) * 32];
    __bf16* bl1 = &Bs[(wid * 32 + 16) * 32];

    // fragment-read element offset: slot = quad ^ (row&3), row&3 = fr&3
    int co = (quad ^ (fr & 3)) * 8;

    for (int k0 = 0; k0 < K; k0 += 32) {
        async_ld16(ag, al0);
        async_ld16(ag + (size_t)16 * K, al1);
        async_ld16(bg, bl0);
        async_ld16(bg + (size_t)16 * K, bl1);
        ag += 32; bg += 32;
        __syncthreads();
        bf8_t af[4], bfr[4];
#pragma unroll
        for (int mi = 0; mi < 4; ++mi)
            af[mi] = *reinterpret_cast<const bf8_t*>(&As[(wm + mi * 16 + fr) * 32 + co]);
#pragma unroll
        for (int ni = 0; ni < 4; ++ni)
            bfr[ni] = *reinterpret_cast<const bf8_t*>(&Bs[(wn + ni * 16 + fr) * 32 + co]);
#pragma unroll
        for (int mi = 0; mi < 4; ++mi)
#pragma unroll
            for (int ni = 0; ni < 4; ++ni)
                acc[mi][ni] = __builtin_amdgcn_mfma_f32_16x16x32_bf16(af[mi], bfr[ni], acc[mi][ni], 0, 0, 0);
        __syncthreads();
    }

    // ---- epilogue: LDS transpose, 4 chunks of 32 rows x 128 cols ----
    const int lrbase = (wm >> 6) * 16 + quad * 4;
#pragma unroll
    for (int mi = 0; mi < 4; ++mi) {
        __syncthreads();
#pragma unroll
        for (int ni = 0; ni < 4; ++ni) {
            int col = wn + ni * 16 + fr;
#pragma unroll
            for (int r = 0; r < 4; ++r)
                cs[(lrbase + r) * 132 + col] = acc[mi][ni][r];
        }
        __syncthreads();
#pragma unroll
        for (int p = 0; p < 4; ++p) {
            int lr = p * 8 + (tid >> 5);
            int c = (tid & 31) * 4;
            int gr = m0 + ((lr < 16) ? (mi * 16 + lr) : (64 + mi * 16 + (lr - 16)));
            f4_t v = *reinterpret_cast<const f4_t*>(&cs[lr * 132 + c]);
            f4_t bv = *reinterpret_cast<const f4_t*>(&bias[n0 + c]);
            v = v + bv;
            if (EPI == 0) {
                bf4_t o;
#pragma unroll
                for (int q = 0; q < 4; ++q) o[q] = (__bf16)gelu_f(v[q]);
                *reinterpret_cast<bf4_t*>(&outb[(size_t)gr * N + n0 + c]) = o;
            } else {
                f4_t rv = *reinterpret_cast<const f4_t*>(&res[(size_t)gr * N + n0 + c]);
                float kp = keep[gr];
                f4_t o;
#pragma unroll
                for (int q = 0; q < 4; ++q) o[q] = (v[q] + rv[q]) * kp;
                *reinterpret_cast<f4_t*>(&outf[(size_t)gr * N + n0 + c]) = o;
            }
        }
    }
}

// ---------------- GRN (general path, gated by flag; no-op at ~0 cost when flag=0) ----------------
__global__ __launch_bounds__(1024) void grn_reduce_kernel(const __bf16* __restrict__ hh,
                                                          float* __restrict__ gsum,
                                                          const int* __restrict__ flag, int l)
{
    if (!flag[l]) return;
    int b = blockIdx.x;
    int i = threadIdx.x;               // channel 0..1023
    float acc = 0.f;
    for (int s = 0; s < SS; ++s) {
        float v = (float)hh[((size_t)b * SS + s) * II + i];
        acc += v * v;
    }
    gsum[b * II + i] = acc;
}

__global__ __launch_bounds__(256) void grn_scale_kernel(const float* __restrict__ gsum,
                                                        const float* __restrict__ gg,
                                                        float* __restrict__ scale,
                                                        const int* __restrict__ flag, int l)
{
    if (!flag[l]) return;
    int b = blockIdx.x, tid = threadIdx.x;
    float gx[4];
    float s = 0.f;
#pragma unroll
    for (int j = 0; j < 4; ++j) {
        gx[j] = sqrtf(gsum[b * II + tid + j * 256]);
        s += gx[j];
    }
    __shared__ float red[256];
    red[tid] = s;
    __syncthreads();
    for (int off = 128; off > 0; off >>= 1) {
        if (tid < off) red[tid] += red[tid + off];
        __syncthreads();
    }
    float mean = red[0] / II;
#pragma unroll
    for (int j = 0; j < 4; ++j) {
        int i = tid + j * 256;
        float nx = gx[j] / (mean + 1e-6f);
        scale[b * II + i] = 1.f + gg[l * II + i] * nx;
    }
}

__global__ __launch_bounds__(256) void grn_apply_kernel(__bf16* __restrict__ hh,
                                                        const float* __restrict__ scale,
                                                        const float* __restrict__ gb,
                                                        const int* __restrict__ flag, int l)
{
    if (!flag[l]) return;
    int i = blockIdx.x * 256 + threadIdx.x;
    int b = blockIdx.y;
    float sc_ = scale[b * II + i];
    float off = gb[l * II + i];
    if (!__any(sc_ != 1.f || off != 0.f)) return;
    for (int s = 0; s < SS; ++s) {
        size_t idx = ((size_t)b * SS + s) * II + i;
        hh[idx] = (__bf16)((float)hh[idx] * sc_ + off);
    }
}

// ---------------- final resample / gather ----------------
__global__ __launch_bounds__(128) void gather_kernel(const float* __restrict__ x,
                                                     const int* __restrict__ counts,
                                                     const int* __restrict__ vpos,
                                                     float* __restrict__ out)
{
    int m = blockIdx.x;
    int b = m >> 11;
    int t = m & (SS - 1);
    int A = counts[2 * b], Vn = counts[2 * b + 1];
    int d = threadIdx.x * 4;
    f4_t o = {0.f, 0.f, 0.f, 0.f};
    if (t < A && Vn > 0) {
        int Vs = Vn;
        int base = A / Vs, rem = A % Vs;
        int nb = Vs - rem;
        int split = nb * base;
        int bb = base > 1 ? base : 1;
        int j = (t < split) ? (t / bb) : (nb + (t - split) / (base + 1));
        if (j > Vs - 1) j = Vs - 1;
        int src = vpos[b * SS + j];
        o = *reinterpret_cast<const f4_t*>(&x[((size_t)b * SS + src) * DD + d]);
    }
    *reinterpret_cast<f4_t*>(&out[(size_t)m * DD + d]) = o;
}

// ---------------- launch ----------------
extern "C" void kernel_launch(void* const* d_in, const int* in_sizes, int n_in,
                              void* d_out, int out_size, void* d_ws, size_t ws_size,
                              hipStream_t stream)
{
    const int*   text  = (const int*)d_in[0];
    const int*   audio = (const int*)d_in[1];
    const float* table = (const float*)d_in[3];
    const float* freq  = (const float*)d_in[4];
    const float* dw_w  = (const float*)d_in[5];
    const float* dw_b  = (const float*)d_in[6];
    const float* ln_g  = (const float*)d_in[7];
    const float* ln_b  = (const float*)d_in[8];
    const float* w1    = (const float*)d_in[9];
    const float* b1    = (const float*)d_in[10];
    const float* grn_g = (const float*)d_in[11];
    const float* grn_b = (const float*)d_in[12];
    const float* w2    = (const float*)d_in[13];
    const float* b2    = (const float*)d_in[14];

    char* ws = (char*)d_ws;
    float*  x      = (float*)(ws + 0);                 // 64 MB
    __bf16* hn     = (__bf16*)(ws + 67108864);         // 32 MB
    __bf16* hh     = (__bf16*)(ws + 100663296);        // 64 MB
    __bf16* wt1    = (__bf16*)(ws + 167772160);        // 4 MB
    __bf16* wt2    = (__bf16*)(ws + 171966464);        // 4 MB
    float*  keepf  = (float*)(ws + 176160768);         // 128 KB
    int*    counts = (int*)(ws + 176291840);           // 128 B
    int*    vpos   = (int*)(ws + 176291968);           // 128 KB
    float*  gsum   = (float*)(ws + 176423040);         // 64 KB
    float*  gscale = (float*)(ws + 176488576);         // 64 KB
    int*    gflag  = (int*)(ws + 176554112);           // 16 B
    float*  out    = (float*)d_out;

    transpose_bf16_kernel<<<(LL * DD * II + 255) / 256, 256, 0, stream>>>(w1, wt1, DD, II);
    transpose_bf16_kernel<<<(LL * DD * II + 255) / 256, 256, 0, stream>>>(w2, wt2, II, DD);
    grn_flag_kernel<<<LL, 256, 0, stream>>>(grn_g, grn_b, gflag);
    embed_kernel<<<BB * SS, 128, 0, stream>>>(text, table, freq, x, keepf);
    counts_kernel<<<BB, 256, 0, stream>>>(keepf, audio, counts, vpos);

    for (int l = 0; l < LL; ++l) {
        conv_ln_kernel<<<BB * (SS / CT), 256, 0, stream>>>(x, dw_w + l * DD * 7, dw_b + l * DD,
                                                           ln_g + l * DD, ln_b + l * DD, hn);
        gemm_kernel<0><<<dim3((II / 128) * 256), 256, 0, stream>>>(
            hn, wt1 + (size_t)l * DD * II, DD, II, 3, b1 + l * II, hh, nullptr, nullptr, nullptr);
        grn_reduce_kernel<<<BB, 1024, 0, stream>>>(hh, gsum, gflag, l);
        grn_scale_kernel<<<BB, 256, 0, stream>>>(gsum, grn_g, gscale, gflag, l);
        grn_apply_kernel<<<dim3(II / 256, BB), 256, 0, stream>>>(hh, gscale, grn_b, gflag, l);
        gemm_kernel<1><<<dim3((DD / 128) * 256), 256, 0, stream>>>(
            hh, wt2 + (size_t)l * II * DD, II, DD, 2, b2 + l * DD, nullptr, x, x, keepf);
    }

    gather_kernel<<<BB * SS, 128, 0, stream>>>(x, counts, vpos, out);
}

// Round 7
// 748.988 us; speedup vs baseline: 1.1145x; 1.1145x over previous
//
#include <hip/hip_runtime.h>
#include <hip/hip_bf16.h>

#define BB 16
#define TTc 256
#define SS 2048
#define DD 512
#define II 1024
#define LL 4
#define MAXPOSc 4096
#define CT 16   // tokens per conv block

typedef __bf16 bf8_t __attribute__((ext_vector_type(8)));
typedef __bf16 bf4_t __attribute__((ext_vector_type(4)));
typedef float  f4_t  __attribute__((ext_vector_type(4)));

__device__ __forceinline__ void async_ld16(const __bf16* g, __bf16* lds)
{
    __builtin_amdgcn_global_load_lds(
        (const __attribute__((address_space(1))) void*)g,
        (__attribute__((address_space(3))) void*)lds,
        16, 0, 0);
}

// tanh-approx GELU: 0.5 v (1 + tanh(0.7978845608 (v + 0.044715 v^3)))
__device__ __forceinline__ float gelu_f(float v)
{
    float u = 0.7978845608f * v * (1.0f + 0.044715f * v * v);
    float e = __expf(2.0f * u);
    float t = 1.0f - 2.0f * __builtin_amdgcn_rcpf(e + 1.0f);
    return 0.5f * v * (1.0f + t);
}

// ---------------- weight transpose + cast: (L,R,C) f32 -> (L,C,R) bf16 ----------------
__global__ void transpose_bf16_kernel(const float* __restrict__ in, __bf16* __restrict__ out,
                                      int R, int C)
{
    long idx = (long)blockIdx.x * 256 + threadIdx.x;
    long RC = (long)R * C;
    long total = RC * LL;
    if (idx >= total) return;
    int m = (int)(idx / RC);
    long rem = idx - (long)m * RC;
    int c = (int)(rem / R);
    int r = (int)(rem - (long)c * R);
    out[idx] = (__bf16)in[(long)m * RC + (long)r * C + c];
}

// ---------------- GRN flag: any(grn_g != 0 || grn_b != 0) per layer ----------------
__global__ __launch_bounds__(256) void grn_flag_kernel(const float* __restrict__ gg,
                                                       const float* __restrict__ gb,
                                                       int* __restrict__ flag)
{
    int l = blockIdx.x;
    __shared__ int any_s;
    if (threadIdx.x == 0) any_s = 0;
    __syncthreads();
    int a = 0;
    for (int i = threadIdx.x; i < II; i += 256)
        a |= (gg[l * II + i] != 0.f) | (gb[l * II + i] != 0.f);
    if (a) atomicOr(&any_s, 1);
    __syncthreads();
    if (threadIdx.x == 0) flag[l] = any_s;
}

// ---------------- embedding + rope-add + mask -> bf16 x ----------------
__global__ __launch_bounds__(128) void embed_kernel(const int* __restrict__ text,
                                                    const float* __restrict__ table,
                                                    const float* __restrict__ freq,
                                                    __bf16* __restrict__ x,
                                                    float* __restrict__ keepf)
{
    int m = blockIdx.x;
    int b = m >> 11;          // S = 2048
    int t = m & (SS - 1);
    int tp = 0;
    if (t < TTc) tp = text[b * TTc + t] + 1;
    if (threadIdx.x == 0) keepf[m] = (tp != 0) ? 1.f : 0.f;
    int d = threadIdx.x * 4;
    bf4_t o;
    o[0] = (__bf16)0.f; o[1] = (__bf16)0.f; o[2] = (__bf16)0.f; o[3] = (__bf16)0.f;
    if (tp != 0) {
        f4_t e = *reinterpret_cast<const f4_t*>(&table[(size_t)tp * DD + d]);
        f4_t f = *reinterpret_cast<const f4_t*>(&freq[(size_t)t * DD + d]);
#pragma unroll
        for (int q = 0; q < 4; ++q) o[q] = (__bf16)(e[q] + f[q]);
    }
    *reinterpret_cast<bf4_t*>(&x[(size_t)m * DD + d]) = o;
}

// ---------------- per-batch counts + valid-position compaction ----------------
__global__ __launch_bounds__(256) void counts_kernel(const float* __restrict__ keepf,
                                                     const int* __restrict__ audio,
                                                     int* __restrict__ counts,
                                                     int* __restrict__ vpos)
{
    int b = blockIdx.x, tid = threadIdx.x;
    int mask8 = 0, cnt = 0;
#pragma unroll
    for (int j = 0; j < 8; ++j) {
        int t = tid * 8 + j;
        int k = keepf[b * SS + t] != 0.f;
        mask8 |= k << j;
        cnt += k;
    }
    __shared__ int sc[256];
    sc[tid] = cnt;
    __syncthreads();
    for (int off = 1; off < 256; off <<= 1) {
        int v = sc[tid];
        int add = (tid >= off) ? sc[tid - off] : 0;
        __syncthreads();
        sc[tid] = v + add;
        __syncthreads();
    }
    int incl = sc[tid];
    int Vn = sc[255];
    int r = incl - cnt;
#pragma unroll
    for (int j = 0; j < 8; ++j)
        if (mask8 & (1 << j)) vpos[b * SS + (r++)] = tid * 8 + j;
    int ac = 0;
#pragma unroll
    for (int j = 0; j < 8; ++j) ac += (audio[b * SS + tid * 8 + j] != 0);
    __syncthreads();
    sc[tid] = ac;
    __syncthreads();
    for (int off = 128; off > 0; off >>= 1) {
        if (tid < off) sc[tid] += sc[tid + off];
        __syncthreads();
    }
    if (tid == 0) { counts[2 * b] = sc[0]; counts[2 * b + 1] = Vn; }
}

// ---------------- depthwise conv(7) + layernorm: bf16 x -> bf16 hn ----------------
__global__ __launch_bounds__(256) void conv_ln_kernel(const __bf16* __restrict__ x,
                                                      const float* __restrict__ w,
                                                      const float* __restrict__ wb,
                                                      const float* __restrict__ g,
                                                      const float* __restrict__ bta,
                                                      __bf16* __restrict__ hn)
{
    __shared__ float xs[CT + 6][DD];   // 44 KB
    int blk = blockIdx.x;
    int b = blk >> 7;                  // SS/CT = 128 blocks per batch
    int t0 = (blk & 127) * CT;
    int tid = threadIdx.x;
    const __bf16* xb = x + (size_t)b * SS * DD;
#pragma unroll
    for (int it = 0; it < (CT + 6) * (DD / 4) / 256; ++it) {
        int i = it * 256 + tid;
        int ri = i >> 7;               // DD/4 = 128
        int c4 = i & 127;
        int tr = t0 - 3 + ri;
        f4_t v = {0.f, 0.f, 0.f, 0.f};
        if (tr >= 0 && tr < SS) {
            bf4_t bv = *reinterpret_cast<const bf4_t*>(&xb[(size_t)tr * DD + c4 * 4]);
#pragma unroll
            for (int q = 0; q < 4; ++q) v[q] = (float)bv[q];
        }
        *reinterpret_cast<f4_t*>(&xs[ri][c4 * 4]) = v;
    }
    __syncthreads();
    int tt = tid >> 4;                 // token within tile 0..15
    int lg = tid & 15;
    float hv[32];
    float s = 0.f, s2 = 0.f;
#pragma unroll
    for (int j = 0; j < 8; ++j) {
        int c = lg * 4 + j * 64;
        float a0 = wb[c], a1 = wb[c + 1], a2 = wb[c + 2], a3 = wb[c + 3];
#pragma unroll
        for (int k = 0; k < 7; ++k) {
            f4_t xv = *reinterpret_cast<const f4_t*>(&xs[tt + k][c]);
            a0 += xv[0] * w[(c + 0) * 7 + k];
            a1 += xv[1] * w[(c + 1) * 7 + k];
            a2 += xv[2] * w[(c + 2) * 7 + k];
            a3 += xv[3] * w[(c + 3) * 7 + k];
        }
        hv[j * 4 + 0] = a0; hv[j * 4 + 1] = a1; hv[j * 4 + 2] = a2; hv[j * 4 + 3] = a3;
        s += a0 + a1 + a2 + a3;
        s2 += a0 * a0 + a1 * a1 + a2 * a2 + a3 * a3;
    }
#pragma unroll
    for (int off = 8; off > 0; off >>= 1) {
        s  += __shfl_down(s, off, 16);
        s2 += __shfl_down(s2, off, 16);
    }
    s  = __shfl(s, 0, 16);
    s2 = __shfl(s2, 0, 16);
    float mu = s / DD;
    float rstd = rsqrtf(s2 / DD - mu * mu + 1e-6f);
    __bf16* hr = hn + ((size_t)b * SS + t0 + tt) * DD;
#pragma unroll
    for (int j = 0; j < 8; ++j) {
        int c = lg * 4 + j * 64;
        bf4_t o;
#pragma unroll
        for (int q = 0; q < 4; ++q)
            o[q] = (__bf16)((hv[j * 4 + q] - mu) * rstd * g[c + q] + bta[c + q]);
        *reinterpret_cast<bf4_t*>(&hr[c]) = o;
    }
}

// ---------------- bf16 MFMA GEMM: C[M,N] = A[M,K] x Wt[N,K]^T ----------------
// EXACT R3 K-loop (fastest measured): BK=32, unpadded [128][32] tiles,
// global_load_lds width=16 staging, XCD swizzle, LDS-transpose epilogue.
// EPI 0: hh_bf16 = gelu(acc + bias)                      (GEMM1)
// EPI 1: x_bf16  = (acc + bias + res_bf16) * keep[m]     (GEMM2, in-place residual)
template <int EPI>
__global__ __launch_bounds__(256) void gemm_kernel(const __bf16* __restrict__ A,
                                                   const __bf16* __restrict__ Wt,
                                                   int K, int N, int nlog,
                                                   const float* __restrict__ bias,
                                                   __bf16* __restrict__ outb,
                                                   const __bf16* __restrict__ res,
                                                   const float* __restrict__ keep)
{
    __shared__ float smem[4224];               // 16.9 KB arena
    __bf16* As = (__bf16*)smem;                // 128x32 bf16 = 8 KB
    __bf16* Bs = As + 128 * 32;                // 8 KB
    float*  cs = smem;                         // epilogue 32x132 f32

    int tid = threadIdx.x;
    int lane = tid & 63, wid = tid >> 6;

    // XCD-aware swizzle: consecutive slots within an XCD share the M-tile.
    int idx = blockIdx.x;
    int xcd = idx & 7;
    int s = idx >> 3;
    int n_t = s & ((1 << nlog) - 1);
    int m_t = ((s >> nlog) << 3) | xcd;
    int n0 = n_t * 128, m0 = m_t * 128;

    f4_t acc[4][4];
#pragma unroll
    for (int i = 0; i < 4; ++i)
#pragma unroll
        for (int j = 0; j < 4; ++j) { f4_t z = {0.f, 0.f, 0.f, 0.f}; acc[i][j] = z; }

    const int wm = (wid >> 1) * 64, wn = (wid & 1) * 64;
    int fr = lane & 15, quad = lane >> 4;

    int srow = wid * 32 + (lane >> 2);
    int scol = (lane & 3) * 8;
    const __bf16* ag = &A[(size_t)(m0 + srow) * K + scol];
    const __bf16* bg = &Wt[(size_t)(n0 + srow) * K + scol];
    __bf16* al0 = &As[(wid * 32) * 32];
    __bf16* al1 = &As[(wid * 32 + 16) * 32];
    __bf16* bl0 = &Bs[(wid * 32) * 32];
    __bf16* bl1 = &Bs[(wid * 32 + 16) * 32];

    for (int k0 = 0; k0 < K; k0 += 32) {
        async_ld16(ag, al0);
        async_ld16(ag + (size_t)16 * K, al1);
        async_ld16(bg, bl0);
        async_ld16(bg + (size_t)16 * K, bl1);
        ag += 32; bg += 32;
        __syncthreads();
        bf8_t af[4], bfr[4];
#pragma unroll
        for (int mi = 0; mi < 4; ++mi)
            af[mi] = *reinterpret_cast<const bf8_t*>(&As[(wm + mi * 16 + fr) * 32 + quad * 8]);
#pragma unroll
        for (int ni = 0; ni < 4; ++ni)
            bfr[ni] = *reinterpret_cast<const bf8_t*>(&Bs[(wn + ni * 16 + fr) * 32 + quad * 8]);
#pragma unroll
        for (int mi = 0; mi < 4; ++mi)
#pragma unroll
            for (int ni = 0; ni < 4; ++ni)
                acc[mi][ni] = __builtin_amdgcn_mfma_f32_16x16x32_bf16(af[mi], bfr[ni], acc[mi][ni], 0, 0, 0);
        __syncthreads();
    }

    // ---- epilogue: LDS transpose, 4 chunks of 32 rows x 128 cols ----
    const int lrbase = (wm >> 6) * 16 + quad * 4;
#pragma unroll
    for (int mi = 0; mi < 4; ++mi) {
        __syncthreads();
#pragma unroll
        for (int ni = 0; ni < 4; ++ni) {
            int col = wn + ni * 16 + fr;
#pragma unroll
            for (int r = 0; r < 4; ++r)
                cs[(lrbase + r) * 132 + col] = acc[mi][ni][r];
        }
        __syncthreads();
#pragma unroll
        for (int p = 0; p < 4; ++p) {
            int lr = p * 8 + (tid >> 5);
            int c = (tid & 31) * 4;
            int gr = m0 + ((lr < 16) ? (mi * 16 + lr) : (64 + mi * 16 + (lr - 16)));
            f4_t v = *reinterpret_cast<const f4_t*>(&cs[lr * 132 + c]);
            f4_t bv = *reinterpret_cast<const f4_t*>(&bias[n0 + c]);
            v = v + bv;
            bf4_t o;
            if (EPI == 0) {
#pragma unroll
                for (int q = 0; q < 4; ++q) o[q] = (__bf16)gelu_f(v[q]);
            } else {
                bf4_t rv = *reinterpret_cast<const bf4_t*>(&res[(size_t)gr * N + n0 + c]);
                float kp = keep[gr];
#pragma unroll
                for (int q = 0; q < 4; ++q) o[q] = (__bf16)((v[q] + (float)rv[q]) * kp);
            }
            *reinterpret_cast<bf4_t*>(&outb[(size_t)gr * N + n0 + c]) = o;
        }
    }
}

// ---------------- GRN (general path, gated by flag; no-op at ~0 cost when flag=0) ----------------
__global__ __launch_bounds__(1024) void grn_reduce_kernel(const __bf16* __restrict__ hh,
                                                          float* __restrict__ gsum,
                                                          const int* __restrict__ flag, int l)
{
    if (!flag[l]) return;
    int b = blockIdx.x;
    int i = threadIdx.x;               // channel 0..1023
    float acc = 0.f;
    for (int s = 0; s < SS; ++s) {
        float v = (float)hh[((size_t)b * SS + s) * II + i];
        acc += v * v;
    }
    gsum[b * II + i] = acc;
}

__global__ __launch_bounds__(256) void grn_scale_kernel(const float* __restrict__ gsum,
                                                        const float* __restrict__ gg,
                                                        float* __restrict__ scale,
                                                        const int* __restrict__ flag, int l)
{
    if (!flag[l]) return;
    int b = blockIdx.x, tid = threadIdx.x;
    float gx[4];
    float s = 0.f;
#pragma unroll
    for (int j = 0; j < 4; ++j) {
        gx[j] = sqrtf(gsum[b * II + tid + j * 256]);
        s += gx[j];
    }
    __shared__ float red[256];
    red[tid] = s;
    __syncthreads();
    for (int off = 128; off > 0; off >>= 1) {
        if (tid < off) red[tid] += red[tid + off];
        __syncthreads();
    }
    float mean = red[0] / II;
#pragma unroll
    for (int j = 0; j < 4; ++j) {
        int i = tid + j * 256;
        float nx = gx[j] / (mean + 1e-6f);
        scale[b * II + i] = 1.f + gg[l * II + i] * nx;
    }
}

__global__ __launch_bounds__(256) void grn_apply_kernel(__bf16* __restrict__ hh,
                                                        const float* __restrict__ scale,
                                                        const float* __restrict__ gb,
                                                        const int* __restrict__ flag, int l)
{
    if (!flag[l]) return;
    int i = blockIdx.x * 256 + threadIdx.x;
    int b = blockIdx.y;
    float sc_ = scale[b * II + i];
    float off = gb[l * II + i];
    if (!__any(sc_ != 1.f || off != 0.f)) return;
    for (int s = 0; s < SS; ++s) {
        size_t idx = ((size_t)b * SS + s) * II + i;
        hh[idx] = (__bf16)((float)hh[idx] * sc_ + off);
    }
}

// ---------------- final resample / gather: bf16 x -> f32 out ----------------
__global__ __launch_bounds__(128) void gather_kernel(const __bf16* __restrict__ x,
                                                     const int* __restrict__ counts,
                                                     const int* __restrict__ vpos,
                                                     float* __restrict__ out)
{
    int m = blockIdx.x;
    int b = m >> 11;
    int t = m & (SS - 1);
    int A = counts[2 * b], Vn = counts[2 * b + 1];
    int d = threadIdx.x * 4;
    f4_t o = {0.f, 0.f, 0.f, 0.f};
    if (t < A && Vn > 0) {
        int Vs = Vn;
        int base = A / Vs, rem = A % Vs;
        int nb = Vs - rem;
        int split = nb * base;
        int bb = base > 1 ? base : 1;
        int j = (t < split) ? (t / bb) : (nb + (t - split) / (base + 1));
        if (j > Vs - 1) j = Vs - 1;
        int src = vpos[b * SS + j];
        bf4_t bv = *reinterpret_cast<const bf4_t*>(&x[((size_t)b * SS + src) * DD + d]);
#pragma unroll
        for (int q = 0; q < 4; ++q) o[q] = (float)bv[q];
    }
    *reinterpret_cast<f4_t*>(&out[(size_t)m * DD + d]) = o;
}

// ---------------- launch ----------------
extern "C" void kernel_launch(void* const* d_in, const int* in_sizes, int n_in,
                              void* d_out, int out_size, void* d_ws, size_t ws_size,
                              hipStream_t stream)
{
    const int*   text  = (const int*)d_in[0];
    const int*   audio = (const int*)d_in[1];
    const float* table = (const float*)d_in[3];
    const float* freq  = (const float*)d_in[4];
    const float* dw_w  = (const float*)d_in[5];
    const float* dw_b  = (const float*)d_in[6];
    const float* ln_g  = (const float*)d_in[7];
    const float* ln_b  = (const float*)d_in[8];
    const float* w1    = (const float*)d_in[9];
    const float* b1    = (const float*)d_in[10];
    const float* grn_g = (const float*)d_in[11];
    const float* grn_b = (const float*)d_in[12];
    const float* w2    = (const float*)d_in[13];
    const float* b2    = (const float*)d_in[14];

    char* ws = (char*)d_ws;
    __bf16* x      = (__bf16*)(ws + 0);                // 32 MB
    __bf16* hn     = (__bf16*)(ws + 33554432);         // 32 MB
    __bf16* hh     = (__bf16*)(ws + 67108864);         // 64 MB
    __bf16* wt1    = (__bf16*)(ws + 134217728);        // 4 MB
    __bf16* wt2    = (__bf16*)(ws + 138412032);        // 4 MB
    float*  keepf  = (float*)(ws + 142606336);         // 128 KB
    int*    counts = (int*)(ws + 142737408);           // 128 B
    int*    vpos   = (int*)(ws + 142737536);           // 128 KB
    float*  gsum   = (float*)(ws + 142868608);         // 64 KB
    float*  gscale = (float*)(ws + 142934144);         // 64 KB
    int*    gflag  = (int*)(ws + 142999680);           // 16 B
    float*  out    = (float*)d_out;

    transpose_bf16_kernel<<<(LL * DD * II + 255) / 256, 256, 0, stream>>>(w1, wt1, DD, II);
    transpose_bf16_kernel<<<(LL * DD * II + 255) / 256, 256, 0, stream>>>(w2, wt2, II, DD);
    grn_flag_kernel<<<LL, 256, 0, stream>>>(grn_g, grn_b, gflag);
    embed_kernel<<<BB * SS, 128, 0, stream>>>(text, table, freq, x, keepf);
    counts_kernel<<<BB, 256, 0, stream>>>(keepf, audio, counts, vpos);

    for (int l = 0; l < LL; ++l) {
        conv_ln_kernel<<<BB * (SS / CT), 256, 0, stream>>>(x, dw_w + l * DD * 7, dw_b + l * DD,
                                                           ln_g + l * DD, ln_b + l * DD, hn);
        gemm_kernel<0><<<dim3((II / 128) * 256), 256, 0, stream>>>(
            hn, wt1 + (size_t)l * DD * II, DD, II, 3, b1 + l * II, hh, nullptr, nullptr);
        grn_reduce_kernel<<<BB, 1024, 0, stream>>>(hh, gsum, gflag, l);
        grn_scale_kernel<<<BB, 256, 0, stream>>>(gsum, grn_g, gscale, gflag, l);
        grn_apply_kernel<<<dim3(II / 256, BB), 256, 0, stream>>>(hh, gscale, grn_b, gflag, l);
        gemm_kernel<1><<<dim3((DD / 128) * 256), 256, 0, stream>>>(
            hh, wt2 + (size_t)l * II * DD, II, DD, 2, b2 + l * DD, x, x, keepf);
    }

    gather_kernel<<<BB * SS, 128, 0, stream>>>(x, counts, vpos, out);
}

// Round 8
// 422.937 us; speedup vs baseline: 1.9737x; 1.7709x over previous
//
#include <hip/hip_runtime.h>
#include <hip/hip_bf16.h>

#define BB 16
#define TTc 256
#define SS 2048
#define WW 320         // compact tokens per batch (256 real + boundary/const rows)
#define MC (BB * WW)   // 5120 = 40 * 128
#define DD 512
#define II 1024
#define LL 4
#define MAXPOSc 4096
#define CT 16          // tokens per conv block

typedef __bf16 bf8_t __attribute__((ext_vector_type(8)));
typedef __bf16 bf4_t __attribute__((ext_vector_type(4)));
typedef float  f4_t  __attribute__((ext_vector_type(4)));

__device__ __forceinline__ void async_ld16(const __bf16* g, __bf16* lds)
{
    __builtin_amdgcn_global_load_lds(
        (const __attribute__((address_space(1))) void*)g,
        (__attribute__((address_space(3))) void*)lds,
        16, 0, 0);
}

// tanh-approx GELU: 0.5 v (1 + tanh(0.7978845608 (v + 0.044715 v^3)))
__device__ __forceinline__ float gelu_f(float v)
{
    float u = 0.7978845608f * v * (1.0f + 0.044715f * v * v);
    float e = __expf(2.0f * u);
    float t = 1.0f - 2.0f * __builtin_amdgcn_rcpf(e + 1.0f);
    return 0.5f * v * (1.0f + t);
}

// ---------------- weight transpose + cast: (L,R,C) f32 -> (L,C,R) bf16 ----------------
__global__ void transpose_bf16_kernel(const float* __restrict__ in, __bf16* __restrict__ out,
                                      int R, int C)
{
    long idx = (long)blockIdx.x * 256 + threadIdx.x;
    long RC = (long)R * C;
    long total = RC * LL;
    if (idx >= total) return;
    int m = (int)(idx / RC);
    long rem = idx - (long)m * RC;
    int c = (int)(rem / R);
    int r = (int)(rem - (long)c * R);
    out[idx] = (__bf16)in[(long)m * RC + (long)r * C + c];
}

// ---------------- GRN flag: any(grn_g != 0 || grn_b != 0) per layer ----------------
__global__ __launch_bounds__(256) void grn_flag_kernel(const float* __restrict__ gg,
                                                       const float* __restrict__ gb,
                                                       int* __restrict__ flag)
{
    int l = blockIdx.x;
    __shared__ int any_s;
    if (threadIdx.x == 0) any_s = 0;
    __syncthreads();
    int a = 0;
    for (int i = threadIdx.x; i < II; i += 256)
        a |= (gg[l * II + i] != 0.f) | (gb[l * II + i] != 0.f);
    if (a) atomicOr(&any_s, 1);
    __syncthreads();
    if (threadIdx.x == 0) flag[l] = any_s;
}

// ---------------- embedding + rope-add + mask -> compact bf16 x [B][WW][D] ----------------
__global__ __launch_bounds__(128) void embed_kernel(const int* __restrict__ text,
                                                    const float* __restrict__ table,
                                                    const float* __restrict__ freq,
                                                    __bf16* __restrict__ x,
                                                    float* __restrict__ keepf)
{
    int t = blockIdx.x;               // 0..WW-1
    int b = blockIdx.y;
    int tp = 0;
    if (t < TTc) tp = text[b * TTc + t] + 1;
    int m = b * WW + t;
    if (threadIdx.x == 0) keepf[m] = (tp != 0) ? 1.f : 0.f;
    int d = threadIdx.x * 4;
    bf4_t o;
    o[0] = (__bf16)0.f; o[1] = (__bf16)0.f; o[2] = (__bf16)0.f; o[3] = (__bf16)0.f;
    if (tp != 0) {
        f4_t e = *reinterpret_cast<const f4_t*>(&table[(size_t)tp * DD + d]);
        f4_t f = *reinterpret_cast<const f4_t*>(&freq[(size_t)t * DD + d]);
#pragma unroll
        for (int q = 0; q < 4; ++q) o[q] = (__bf16)(e[q] + f[q]);
    }
    *reinterpret_cast<bf4_t*>(&x[(size_t)m * DD + d]) = o;
}

// ---------------- per-batch counts + valid-position compaction ----------------
// keep is nonzero only for t<256; audio spans full S.
__global__ __launch_bounds__(256) void counts_kernel(const float* __restrict__ keepf,
                                                     const int* __restrict__ audio,
                                                     int* __restrict__ counts,
                                                     int* __restrict__ vpos)
{
    int b = blockIdx.x, tid = threadIdx.x;
    int k = keepf[b * WW + tid] != 0.f;   // tid < 256
    __shared__ int sc[256];
    sc[tid] = k;
    __syncthreads();
    for (int off = 1; off < 256; off <<= 1) {
        int v = sc[tid];
        int add = (tid >= off) ? sc[tid - off] : 0;
        __syncthreads();
        sc[tid] = v + add;
        __syncthreads();
    }
    int incl = sc[tid];
    int Vn = sc[255];
    if (k) vpos[b * 256 + (incl - 1)] = tid;
    int ac = 0;
#pragma unroll
    for (int j = 0; j < 8; ++j) ac += (audio[b * SS + tid * 8 + j] != 0);
    __syncthreads();
    sc[tid] = ac;
    __syncthreads();
    for (int off = 128; off > 0; off >>= 1) {
        if (tid < off) sc[tid] += sc[tid + off];
        __syncthreads();
    }
    if (tid == 0) { counts[2 * b] = sc[0]; counts[2 * b + 1] = Vn; }
}

// ---------------- depthwise conv(7) + layernorm: compact bf16 x -> bf16 hn ----------------
__global__ __launch_bounds__(256) void conv_ln_kernel(const __bf16* __restrict__ x,
                                                      const float* __restrict__ w,
                                                      const float* __restrict__ wb,
                                                      const float* __restrict__ g,
                                                      const float* __restrict__ bta,
                                                      __bf16* __restrict__ hn)
{
    __shared__ float xs[CT + 6][DD];   // 44 KB
    int b = blockIdx.y;
    int t0 = blockIdx.x * CT;
    int tid = threadIdx.x;
    const __bf16* xb = x + (size_t)b * WW * DD;
#pragma unroll
    for (int it = 0; it < (CT + 6) * (DD / 4) / 256; ++it) {
        int i = it * 256 + tid;
        int ri = i >> 7;               // DD/4 = 128
        int c4 = i & 127;
        int tr = t0 - 3 + ri;
        f4_t v = {0.f, 0.f, 0.f, 0.f};
        if (tr >= 0 && tr < WW) {
            bf4_t bv = *reinterpret_cast<const bf4_t*>(&xb[(size_t)tr * DD + c4 * 4]);
#pragma unroll
            for (int q = 0; q < 4; ++q) v[q] = (float)bv[q];
        }
        *reinterpret_cast<f4_t*>(&xs[ri][c4 * 4]) = v;
    }
    __syncthreads();
    int tt = tid >> 4;                 // token within tile 0..15
    int lg = tid & 15;
    float hv[32];
    float s = 0.f, s2 = 0.f;
#pragma unroll
    for (int j = 0; j < 8; ++j) {
        int c = lg * 4 + j * 64;
        float a0 = wb[c], a1 = wb[c + 1], a2 = wb[c + 2], a3 = wb[c + 3];
#pragma unroll
        for (int k = 0; k < 7; ++k) {
            f4_t xv = *reinterpret_cast<const f4_t*>(&xs[tt + k][c]);
            a0 += xv[0] * w[(c + 0) * 7 + k];
            a1 += xv[1] * w[(c + 1) * 7 + k];
            a2 += xv[2] * w[(c + 2) * 7 + k];
            a3 += xv[3] * w[(c + 3) * 7 + k];
        }
        hv[j * 4 + 0] = a0; hv[j * 4 + 1] = a1; hv[j * 4 + 2] = a2; hv[j * 4 + 3] = a3;
        s += a0 + a1 + a2 + a3;
        s2 += a0 * a0 + a1 * a1 + a2 * a2 + a3 * a3;
    }
#pragma unroll
    for (int off = 8; off > 0; off >>= 1) {
        s  += __shfl_down(s, off, 16);
        s2 += __shfl_down(s2, off, 16);
    }
    s  = __shfl(s, 0, 16);
    s2 = __shfl(s2, 0, 16);
    float mu = s / DD;
    float rstd = rsqrtf(s2 / DD - mu * mu + 1e-6f);
    __bf16* hr = hn + ((size_t)b * WW + t0 + tt) * DD;
#pragma unroll
    for (int j = 0; j < 8; ++j) {
        int c = lg * 4 + j * 64;
        bf4_t o;
#pragma unroll
        for (int q = 0; q < 4; ++q)
            o[q] = (__bf16)((hv[j * 4 + q] - mu) * rstd * g[c + q] + bta[c + q]);
        *reinterpret_cast<bf4_t*>(&hr[c]) = o;
    }
}

// ---------------- bf16 MFMA GEMM: C[M,N] = A[M,K] x Wt[N,K]^T ----------------
// R3-proven K-loop: BK=32, unpadded [128][32] tiles, global_load_lds width=16,
// LDS-transpose epilogue. Grid = mtiles << nlog (n-tiles = 1<<nlog).
// EPI 0: hh_bf16 = gelu(acc + bias)                      (GEMM1)
// EPI 1: x_bf16  = (acc + bias + res_bf16) * keep[m]     (GEMM2, in-place residual)
template <int EPI>
__global__ __launch_bounds__(256) void gemm_kernel(const __bf16* __restrict__ A,
                                                   const __bf16* __restrict__ Wt,
                                                   int K, int N, int nlog,
                                                   const float* __restrict__ bias,
                                                   __bf16* __restrict__ outb,
                                                   const __bf16* __restrict__ res,
                                                   const float* __restrict__ keep)
{
    __shared__ float smem[4224];               // 16.9 KB arena
    __bf16* As = (__bf16*)smem;                // 128x32 bf16 = 8 KB
    __bf16* Bs = As + 128 * 32;                // 8 KB
    float*  cs = smem;                         // epilogue 32x132 f32

    int tid = threadIdx.x;
    int lane = tid & 63, wid = tid >> 6;

    int idx = blockIdx.x;
    int n_t = idx & ((1 << nlog) - 1);
    int m_t = idx >> nlog;
    int n0 = n_t * 128, m0 = m_t * 128;

    f4_t acc[4][4];
#pragma unroll
    for (int i = 0; i < 4; ++i)
#pragma unroll
        for (int j = 0; j < 4; ++j) { f4_t z = {0.f, 0.f, 0.f, 0.f}; acc[i][j] = z; }

    const int wm = (wid >> 1) * 64, wn = (wid & 1) * 64;
    int fr = lane & 15, quad = lane >> 4;

    int srow = wid * 32 + (lane >> 2);
    int scol = (lane & 3) * 8;
    const __bf16* ag = &A[(size_t)(m0 + srow) * K + scol];
    const __bf16* bg = &Wt[(size_t)(n0 + srow) * K + scol];
    __bf16* al0 = &As[(wid * 32) * 32];
    __bf16* al1 = &As[(wid * 32 + 16) * 32];
    __bf16* bl0 = &Bs[(wid * 32) * 32];
    __bf16* bl1 = &Bs[(wid * 32 + 16) * 32];

    for (int k0 = 0; k0 < K; k0 += 32) {
        async_ld16(ag, al0);
        async_ld16(ag + (size_t)16 * K, al1);
        async_ld16(bg, bl0);
        async_ld16(bg + (size_t)16 * K, bl1);
        ag += 32; bg += 32;
        __syncthreads();
        bf8_t af[4], bfr[4];
#pragma unroll
        for (int mi = 0; mi < 4; ++mi)
            af[mi] = *reinterpret_cast<const bf8_t*>(&As[(wm + mi * 16 + fr) * 32 + quad * 8]);
#pragma unroll
        for (int ni = 0; ni < 4; ++ni)
            bfr[ni] = *reinterpret_cast<const bf8_t*>(&Bs[(wn + ni * 16 + fr) * 32 + quad * 8]);
#pragma unroll
        for (int mi = 0; mi < 4; ++mi)
#pragma unroll
            for (int ni = 0; ni < 4; ++ni)
                acc[mi][ni] = __builtin_amdgcn_mfma_f32_16x16x32_bf16(af[mi], bfr[ni], acc[mi][ni], 0, 0, 0);
        __syncthreads();
    }

    // ---- epilogue: LDS transpose, 4 chunks of 32 rows x 128 cols ----
    const int lrbase = (wm >> 6) * 16 + quad * 4;
#pragma unroll
    for (int mi = 0; mi < 4; ++mi) {
        __syncthreads();
#pragma unroll
        for (int ni = 0; ni < 4; ++ni) {
            int col = wn + ni * 16 + fr;
#pragma unroll
            for (int r = 0; r < 4; ++r)
                cs[(lrbase + r) * 132 + col] = acc[mi][ni][r];
        }
        __syncthreads();
#pragma unroll
        for (int p = 0; p < 4; ++p) {
            int lr = p * 8 + (tid >> 5);
            int c = (tid & 31) * 4;
            int gr = m0 + ((lr < 16) ? (mi * 16 + lr) : (64 + mi * 16 + (lr - 16)));
            f4_t v = *reinterpret_cast<const f4_t*>(&cs[lr * 132 + c]);
            f4_t bv = *reinterpret_cast<const f4_t*>(&bias[n0 + c]);
            v = v + bv;
            bf4_t o;
            if (EPI == 0) {
#pragma unroll
                for (int q = 0; q < 4; ++q) o[q] = (__bf16)gelu_f(v[q]);
            } else {
                bf4_t rv = *reinterpret_cast<const bf4_t*>(&res[(size_t)gr * N + n0 + c]);
                float kp = keep[gr];
#pragma unroll
                for (int q = 0; q < 4; ++q) o[q] = (__bf16)((v[q] + (float)rv[q]) * kp);
            }
            *reinterpret_cast<bf4_t*>(&outb[(size_t)gr * N + n0 + c]) = o;
        }
    }
}

// ---------------- GRN (general path, gated by flag; exact w/ constant-row correction) ----------------
// Reference sums h*h over the FULL seq (S=2048). Compact rows 0..318 match the
// full-space rows exactly; rows 319.. and all full-space rows >=319 are the
// identical pure-constant row (conv neighborhood all-zero). So:
//   gsum = sum_{s<WW} h^2 + (S - WW) * h[WW-1]^2
__global__ __launch_bounds__(1024) void grn_reduce_kernel(const __bf16* __restrict__ hh,
                                                          float* __restrict__ gsum,
                                                          const int* __restrict__ flag, int l)
{
    if (!flag[l]) return;
    int b = blockIdx.x;
    int i = threadIdx.x;               // channel 0..1023
    float acc = 0.f;
    for (int s = 0; s < WW; ++s) {
        float v = (float)hh[((size_t)b * WW + s) * II + i];
        acc += v * v;
    }
    float c = (float)hh[((size_t)b * WW + WW - 1) * II + i];
    gsum[b * II + i] = acc + (float)(SS - WW) * c * c;
}

__global__ __launch_bounds__(256) void grn_scale_kernel(const float* __restrict__ gsum,
                                                        const float* __restrict__ gg,
                                                        float* __restrict__ scale,
                                                        const int* __restrict__ flag, int l)
{
    if (!flag[l]) return;
    int b = blockIdx.x, tid = threadIdx.x;
    float gx[4];
    float s = 0.f;
#pragma unroll
    for (int j = 0; j < 4; ++j) {
        gx[j] = sqrtf(gsum[b * II + tid + j * 256]);
        s += gx[j];
    }
    __shared__ float red[256];
    red[tid] = s;
    __syncthreads();
    for (int off = 128; off > 0; off >>= 1) {
        if (tid < off) red[tid] += red[tid + off];
        __syncthreads();
    }
    float mean = red[0] / II;
#pragma unroll
    for (int j = 0; j < 4; ++j) {
        int i = tid + j * 256;
        float nx = gx[j] / (mean + 1e-6f);
        scale[b * II + i] = 1.f + gg[l * II + i] * nx;
    }
}

__global__ __launch_bounds__(256) void grn_apply_kernel(__bf16* __restrict__ hh,
                                                        const float* __restrict__ scale,
                                                        const float* __restrict__ gb,
                                                        const int* __restrict__ flag, int l)
{
    if (!flag[l]) return;
    int i = blockIdx.x * 256 + threadIdx.x;
    int b = blockIdx.y;
    float sc_ = scale[b * II + i];
    float off = gb[l * II + i];
    if (!__any(sc_ != 1.f || off != 0.f)) return;
    for (int s = 0; s < WW; ++s) {
        size_t idx = ((size_t)b * WW + s) * II + i;
        hh[idx] = (__bf16)((float)hh[idx] * sc_ + off);
    }
}

// ---------------- final resample / gather: compact bf16 x -> full f32 out ----------------
__global__ __launch_bounds__(128) void gather_kernel(const __bf16* __restrict__ x,
                                                     const int* __restrict__ counts,
                                                     const int* __restrict__ vpos,
                                                     float* __restrict__ out)
{
    int m = blockIdx.x;
    int b = m >> 11;
    int t = m & (SS - 1);
    int A = counts[2 * b], Vn = counts[2 * b + 1];
    int d = threadIdx.x * 4;
    f4_t o = {0.f, 0.f, 0.f, 0.f};
    if (t < A && Vn > 0) {
        int Vs = Vn;
        int base = A / Vs, rem = A % Vs;
        int nb = Vs - rem;
        int split = nb * base;
        int bb = base > 1 ? base : 1;
        int j = (t < split) ? (t / bb) : (nb + (t - split) / (base + 1));
        if (j > Vs - 1) j = Vs - 1;
        int src = vpos[b * 256 + j];
        bf4_t bv = *reinterpret_cast<const bf4_t*>(&x[((size_t)b * WW + src) * DD + d]);
#pragma unroll
        for (int q = 0; q < 4; ++q) o[q] = (float)bv[q];
    }
    *reinterpret_cast<f4_t*>(&out[(size_t)m * DD + d]) = o;
}

// ---------------- launch ----------------
extern "C" void kernel_launch(void* const* d_in, const int* in_sizes, int n_in,
                              void* d_out, int out_size, void* d_ws, size_t ws_size,
                              hipStream_t stream)
{
    const int*   text  = (const int*)d_in[0];
    const int*   audio = (const int*)d_in[1];
    const float* table = (const float*)d_in[3];
    const float* freq  = (const float*)d_in[4];
    const float* dw_w  = (const float*)d_in[5];
    const float* dw_b  = (const float*)d_in[6];
    const float* ln_g  = (const float*)d_in[7];
    const float* ln_b  = (const float*)d_in[8];
    const float* w1    = (const float*)d_in[9];
    const float* b1    = (const float*)d_in[10];
    const float* grn_g = (const float*)d_in[11];
    const float* grn_b = (const float*)d_in[12];
    const float* w2    = (const float*)d_in[13];
    const float* b2    = (const float*)d_in[14];

    char* ws = (char*)d_ws;
    __bf16* x      = (__bf16*)(ws + 0);                // MC*DD*2   = 5 MB
    __bf16* hn     = (__bf16*)(ws + 6291456);          // 5 MB
    __bf16* hh     = (__bf16*)(ws + 12582912);         // MC*II*2   = 10 MB
    __bf16* wt1    = (__bf16*)(ws + 25165824);         // 4 MB
    __bf16* wt2    = (__bf16*)(ws + 29360128);         // 4 MB
    float*  keepf  = (float*)(ws + 33554432);          // MC*4 = 20 KB
    int*    counts = (int*)(ws + 33685504);            // 128 B
    int*    vpos   = (int*)(ws + 33685632);            // 16*256*4 = 16 KB
    float*  gsum   = (float*)(ws + 33816576);          // 64 KB
    float*  gscale = (float*)(ws + 33882112);          // 64 KB
    int*    gflag  = (int*)(ws + 33947648);            // 16 B
    float*  out    = (float*)d_out;

    transpose_bf16_kernel<<<(LL * DD * II + 255) / 256, 256, 0, stream>>>(w1, wt1, DD, II);
    transpose_bf16_kernel<<<(LL * DD * II + 255) / 256, 256, 0, stream>>>(w2, wt2, II, DD);
    grn_flag_kernel<<<LL, 256, 0, stream>>>(grn_g, grn_b, gflag);
    embed_kernel<<<dim3(WW, BB), 128, 0, stream>>>(text, table, freq, x, keepf);
    counts_kernel<<<BB, 256, 0, stream>>>(keepf, audio, counts, vpos);

    for (int l = 0; l < LL; ++l) {
        conv_ln_kernel<<<dim3(WW / CT, BB), 256, 0, stream>>>(x, dw_w + l * DD * 7, dw_b + l * DD,
                                                              ln_g + l * DD, ln_b + l * DD, hn);
        gemm_kernel<0><<<(MC / 128) << 3, 256, 0, stream>>>(
            hn, wt1 + (size_t)l * DD * II, DD, II, 3, b1 + l * II, hh, nullptr, nullptr);
        grn_reduce_kernel<<<BB, 1024, 0, stream>>>(hh, gsum, gflag, l);
        grn_scale_kernel<<<BB, 256, 0, stream>>>(gsum, grn_g, gscale, gflag, l);
        grn_apply_kernel<<<dim3(II / 256, BB), 256, 0, stream>>>(hh, gscale, grn_b, gflag, l);
        gemm_kernel<1><<<(MC / 128) << 2, 256, 0, stream>>>(
            hh, wt2 + (size_t)l * II * DD, II, DD, 2, b2 + l * DD, x, x, keepf);
    }

    gather_kernel<<<BB * SS, 128, 0, stream>>>(x, counts, vpos, out);
}

// Round 9
// 349.568 us; speedup vs baseline: 2.3879x; 1.2099x over previous
//
#include <hip/hip_runtime.h>
#include <hip/hip_bf16.h>

#define BB 16
#define TTc 256
#define SS 2048
#define WW 320         // compact tokens per batch (256 real + boundary/const rows)
#define MC (BB * WW)   // 5120 = 80 * 64
#define DD 512
#define II 1024
#define LL 4
#define MAXPOSc 4096
#define CT 16          // tokens per conv block

typedef __bf16 bf8_t __attribute__((ext_vector_type(8)));
typedef __bf16 bf4_t __attribute__((ext_vector_type(4)));
typedef float  f4_t  __attribute__((ext_vector_type(4)));

__device__ __forceinline__ void async_ld16(const __bf16* g, __bf16* lds)
{
    __builtin_amdgcn_global_load_lds(
        (const __attribute__((address_space(1))) void*)g,
        (__attribute__((address_space(3))) void*)lds,
        16, 0, 0);
}

// tanh-approx GELU: 0.5 v (1 + tanh(0.7978845608 (v + 0.044715 v^3)))
__device__ __forceinline__ float gelu_f(float v)
{
    float u = 0.7978845608f * v * (1.0f + 0.044715f * v * v);
    float e = __expf(2.0f * u);
    float t = 1.0f - 2.0f * __builtin_amdgcn_rcpf(e + 1.0f);
    return 0.5f * v * (1.0f + t);
}

// ---------------- fused weight transpose + cast (LDS-tiled, coalesced both ways) ----
// blocks 0..2047: w1 (R=512,C=1024); blocks 2048..4095: w2 (R=1024,C=512)
__global__ __launch_bounds__(256) void transpose_fused_kernel(const float* __restrict__ w1,
                                                              const float* __restrict__ w2,
                                                              __bf16* __restrict__ o1,
                                                              __bf16* __restrict__ o2)
{
    __shared__ float ld[32][33];
    int blk = blockIdx.x;
    const float* in;
    __bf16* out;
    int R, C, t;
    if (blk < 2048) { in = w1; out = o1; R = DD; C = II; t = blk; }
    else            { in = w2; out = o2; R = II; C = DD; t = blk - 2048; }
    int tpl = (R / 32) * (C / 32);        // tiles per layer = 512
    int l = t / tpl; t -= l * tpl;
    int tr = t / (C / 32), tc = t % (C / 32);
    long base = (long)l * R * C;
    int ty = threadIdx.x >> 5, tx = threadIdx.x & 31;
#pragma unroll
    for (int i = 0; i < 4; ++i) {
        int r = tr * 32 + ty + i * 8;
        ld[ty + i * 8][tx] = in[base + (long)r * C + tc * 32 + tx];
    }
    __syncthreads();
#pragma unroll
    for (int i = 0; i < 4; ++i) {
        int c = tc * 32 + ty + i * 8;
        out[base + (long)c * R + tr * 32 + tx] = (__bf16)ld[tx][ty + i * 8];
    }
}

// ---------------- GRN flag: any(grn_g != 0 || grn_b != 0) per layer ----------------
__global__ __launch_bounds__(256) void grn_flag_kernel(const float* __restrict__ gg,
                                                       const float* __restrict__ gb,
                                                       int* __restrict__ flag)
{
    int l = blockIdx.x;
    __shared__ int any_s;
    if (threadIdx.x == 0) any_s = 0;
    __syncthreads();
    int a = 0;
    for (int i = threadIdx.x; i < II; i += 256)
        a |= (gg[l * II + i] != 0.f) | (gb[l * II + i] != 0.f);
    if (a) atomicOr(&any_s, 1);
    __syncthreads();
    if (threadIdx.x == 0) flag[l] = any_s;
}

// ---------------- embedding + rope-add + mask -> compact bf16 x [B][WW][D] ----------------
__global__ __launch_bounds__(128) void embed_kernel(const int* __restrict__ text,
                                                    const float* __restrict__ table,
                                                    const float* __restrict__ freq,
                                                    __bf16* __restrict__ x,
                                                    float* __restrict__ keepf)
{
    int t = blockIdx.x;               // 0..WW-1
    int b = blockIdx.y;
    int tp = 0;
    if (t < TTc) tp = text[b * TTc + t] + 1;
    int m = b * WW + t;
    if (threadIdx.x == 0) keepf[m] = (tp != 0) ? 1.f : 0.f;
    int d = threadIdx.x * 4;
    bf4_t o;
    o[0] = (__bf16)0.f; o[1] = (__bf16)0.f; o[2] = (__bf16)0.f; o[3] = (__bf16)0.f;
    if (tp != 0) {
        f4_t e = *reinterpret_cast<const f4_t*>(&table[(size_t)tp * DD + d]);
        f4_t f = *reinterpret_cast<const f4_t*>(&freq[(size_t)t * DD + d]);
#pragma unroll
        for (int q = 0; q < 4; ++q) o[q] = (__bf16)(e[q] + f[q]);
    }
    *reinterpret_cast<bf4_t*>(&x[(size_t)m * DD + d]) = o;
}

// ---------------- per-batch counts + valid-position compaction ----------------
__global__ __launch_bounds__(256) void counts_kernel(const float* __restrict__ keepf,
                                                     const int* __restrict__ audio,
                                                     int* __restrict__ counts,
                                                     int* __restrict__ vpos)
{
    int b = blockIdx.x, tid = threadIdx.x;
    int k = keepf[b * WW + tid] != 0.f;   // tid < 256
    __shared__ int sc[256];
    sc[tid] = k;
    __syncthreads();
    for (int off = 1; off < 256; off <<= 1) {
        int v = sc[tid];
        int add = (tid >= off) ? sc[tid - off] : 0;
        __syncthreads();
        sc[tid] = v + add;
        __syncthreads();
    }
    int incl = sc[tid];
    int Vn = sc[255];
    if (k) vpos[b * 256 + (incl - 1)] = tid;
    int ac = 0;
#pragma unroll
    for (int j = 0; j < 8; ++j) ac += (audio[b * SS + tid * 8 + j] != 0);
    __syncthreads();
    sc[tid] = ac;
    __syncthreads();
    for (int off = 128; off > 0; off >>= 1) {
        if (tid < off) sc[tid] += sc[tid + off];
        __syncthreads();
    }
    if (tid == 0) { counts[2 * b] = sc[0]; counts[2 * b + 1] = Vn; }
}

// ---------------- depthwise conv(7) + layernorm: compact bf16 x -> bf16 hn ----------------
__global__ __launch_bounds__(256) void conv_ln_kernel(const __bf16* __restrict__ x,
                                                      const float* __restrict__ w,
                                                      const float* __restrict__ wb,
                                                      const float* __restrict__ g,
                                                      const float* __restrict__ bta,
                                                      __bf16* __restrict__ hn)
{
    __shared__ float xs[CT + 6][DD];   // 44 KB
    int b = blockIdx.y;
    int t0 = blockIdx.x * CT;
    int tid = threadIdx.x;
    const __bf16* xb = x + (size_t)b * WW * DD;
#pragma unroll
    for (int it = 0; it < (CT + 6) * (DD / 4) / 256; ++it) {
        int i = it * 256 + tid;
        int ri = i >> 7;               // DD/4 = 128
        int c4 = i & 127;
        int tr = t0 - 3 + ri;
        f4_t v = {0.f, 0.f, 0.f, 0.f};
        if (tr >= 0 && tr < WW) {
            bf4_t bv = *reinterpret_cast<const bf4_t*>(&xb[(size_t)tr * DD + c4 * 4]);
#pragma unroll
            for (int q = 0; q < 4; ++q) v[q] = (float)bv[q];
        }
        *reinterpret_cast<f4_t*>(&xs[ri][c4 * 4]) = v;
    }
    __syncthreads();
    int tt = tid >> 4;                 // token within tile 0..15
    int lg = tid & 15;
    float hv[32];
    float s = 0.f, s2 = 0.f;
#pragma unroll
    for (int j = 0; j < 8; ++j) {
        int c = lg * 4 + j * 64;
        float a0 = wb[c], a1 = wb[c + 1], a2 = wb[c + 2], a3 = wb[c + 3];
#pragma unroll
        for (int k = 0; k < 7; ++k) {
            f4_t xv = *reinterpret_cast<const f4_t*>(&xs[tt + k][c]);
            a0 += xv[0] * w[(c + 0) * 7 + k];
            a1 += xv[1] * w[(c + 1) * 7 + k];
            a2 += xv[2] * w[(c + 2) * 7 + k];
            a3 += xv[3] * w[(c + 3) * 7 + k];
        }
        hv[j * 4 + 0] = a0; hv[j * 4 + 1] = a1; hv[j * 4 + 2] = a2; hv[j * 4 + 3] = a3;
        s += a0 + a1 + a2 + a3;
        s2 += a0 * a0 + a1 * a1 + a2 * a2 + a3 * a3;
    }
#pragma unroll
    for (int off = 8; off > 0; off >>= 1) {
        s  += __shfl_down(s, off, 16);
        s2 += __shfl_down(s2, off, 16);
    }
    s  = __shfl(s, 0, 16);
    s2 = __shfl(s2, 0, 16);
    float mu = s / DD;
    float rstd = rsqrtf(s2 / DD - mu * mu + 1e-6f);
    __bf16* hr = hn + ((size_t)b * WW + t0 + tt) * DD;
#pragma unroll
    for (int j = 0; j < 8; ++j) {
        int c = lg * 4 + j * 64;
        bf4_t o;
#pragma unroll
        for (int q = 0; q < 4; ++q)
            o[q] = (__bf16)((hv[j * 4 + q] - mu) * rstd * g[c + q] + bta[c + q]);
        *reinterpret_cast<bf4_t*>(&hr[c]) = o;
    }
}

// ---------------- bf16 MFMA GEMM: C[M,N] = A[M,K] x Wt[N,K]^T ----------------
// 64x128 tile (more blocks -> cross-block latency hiding at small M), BK=32,
// R3-proven staging (global_load_lds width=16, unpadded tiles) + LDS-transpose
// epilogue. Grid = mtiles << nlog.
// EPI 0: hh_bf16 = gelu(acc + bias)                      (GEMM1)
// EPI 1: x_bf16  = (acc + bias + res_bf16) * keep[m]     (GEMM2, in-place residual)
template <int EPI>
__global__ __launch_bounds__(256) void gemm_kernel(const __bf16* __restrict__ A,
                                                   const __bf16* __restrict__ Wt,
                                                   int K, int N, int nlog,
                                                   const float* __restrict__ bias,
                                                   __bf16* __restrict__ outb,
                                                   const __bf16* __restrict__ res,
                                                   const float* __restrict__ keep)
{
    __shared__ float smem[4224];               // 16.9 KB arena
    __bf16* As = (__bf16*)smem;                // 64x32 bf16 = 4 KB
    __bf16* Bs = As + 64 * 32;                 // 128x32 bf16 = 8 KB
    float*  cs = smem;                         // epilogue 32x132 f32

    int tid = threadIdx.x;
    int lane = tid & 63, wid = tid >> 6;

    int idx = blockIdx.x;
    int n_t = idx & ((1 << nlog) - 1);
    int m_t = idx >> nlog;
    int n0 = n_t * 128, m0 = m_t * 64;

    f4_t acc[2][4];
#pragma unroll
    for (int i = 0; i < 2; ++i)
#pragma unroll
        for (int j = 0; j < 4; ++j) { f4_t z = {0.f, 0.f, 0.f, 0.f}; acc[i][j] = z; }

    const int wm = (wid >> 1) * 32, wn = (wid & 1) * 64;
    int fr = lane & 15, quad = lane >> 4;

    int r4 = lane >> 2;
    int scol = (lane & 3) * 8;
    const __bf16* ag = &A[(size_t)(m0 + wid * 16 + r4) * K + scol];
    const __bf16* bg = &Wt[(size_t)(n0 + wid * 32 + r4) * K + scol];
    __bf16* al = &As[(wid * 16) * 32];
    __bf16* bl0 = &Bs[(wid * 32) * 32];
    __bf16* bl1 = &Bs[(wid * 32 + 16) * 32];

    for (int k0 = 0; k0 < K; k0 += 32) {
        async_ld16(ag, al);
        async_ld16(bg, bl0);
        async_ld16(bg + (size_t)16 * K, bl1);
        ag += 32; bg += 32;
        __syncthreads();
        bf8_t af[2], bfr[4];
#pragma unroll
        for (int mi = 0; mi < 2; ++mi)
            af[mi] = *reinterpret_cast<const bf8_t*>(&As[(wm + mi * 16 + fr) * 32 + quad * 8]);
#pragma unroll
        for (int ni = 0; ni < 4; ++ni)
            bfr[ni] = *reinterpret_cast<const bf8_t*>(&Bs[(wn + ni * 16 + fr) * 32 + quad * 8]);
#pragma unroll
        for (int mi = 0; mi < 2; ++mi)
#pragma unroll
            for (int ni = 0; ni < 4; ++ni)
                acc[mi][ni] = __builtin_amdgcn_mfma_f32_16x16x32_bf16(af[mi], bfr[ni], acc[mi][ni], 0, 0, 0);
        __syncthreads();
    }

    // ---- epilogue: LDS transpose, 2 chunks of 32 rows x 128 cols ----
    const int lrbase = (wm >> 5) * 16 + quad * 4;
#pragma unroll
    for (int mi = 0; mi < 2; ++mi) {
        __syncthreads();
#pragma unroll
        for (int ni = 0; ni < 4; ++ni) {
            int col = wn + ni * 16 + fr;
#pragma unroll
            for (int r = 0; r < 4; ++r)
                cs[(lrbase + r) * 132 + col] = acc[mi][ni][r];
        }
        __syncthreads();
#pragma unroll
        for (int p = 0; p < 4; ++p) {
            int lr = p * 8 + (tid >> 5);
            int c = (tid & 31) * 4;
            int gr = m0 + ((lr < 16) ? (mi * 16 + lr) : (32 + mi * 16 + (lr - 16)));
            f4_t v = *reinterpret_cast<const f4_t*>(&cs[lr * 132 + c]);
            f4_t bv = *reinterpret_cast<const f4_t*>(&bias[n0 + c]);
            v = v + bv;
            bf4_t o;
            if (EPI == 0) {
#pragma unroll
                for (int q = 0; q < 4; ++q) o[q] = (__bf16)gelu_f(v[q]);
            } else {
                bf4_t rv = *reinterpret_cast<const bf4_t*>(&res[(size_t)gr * N + n0 + c]);
                float kp = keep[gr];
#pragma unroll
                for (int q = 0; q < 4; ++q) o[q] = (__bf16)((v[q] + (float)rv[q]) * kp);
            }
            *reinterpret_cast<bf4_t*>(&outb[(size_t)gr * N + n0 + c]) = o;
        }
    }
}

// ---------------- fused GRN (general path, gated by flag; exact constant-row corr.) ----
// One block per batch: per-channel seq-sum (+ (S-WW)*const^2), block-reduce for
// the channel-mean of sqrt, then apply h = h*(1+g*nx) + b in-place.
__global__ __launch_bounds__(1024) void grn_fused_kernel(__bf16* __restrict__ hh,
                                                         const float* __restrict__ gg,
                                                         const float* __restrict__ gb,
                                                         const int* __restrict__ flag, int l)
{
    if (!flag[l]) return;
    int b = blockIdx.x;
    int i = threadIdx.x;               // channel 0..1023
    float acc = 0.f;
    for (int s = 0; s < WW; ++s) {
        float v = (float)hh[((size_t)b * WW + s) * II + i];
        acc += v * v;
    }
    float c = (float)hh[((size_t)b * WW + WW - 1) * II + i];
    acc += (float)(SS - WW) * c * c;
    float gx = sqrtf(acc);
    __shared__ float red[1024];
    red[i] = gx;
    __syncthreads();
    for (int off = 512; off > 0; off >>= 1) {
        if (i < off) red[i] += red[i + off];
        __syncthreads();
    }
    float mean = red[0] / II;
    float nx = gx / (mean + 1e-6f);
    float sc = 1.f + gg[l * II + i] * nx;
    float off = gb[l * II + i];
    for (int s = 0; s < WW; ++s) {
        size_t idx = ((size_t)b * WW + s) * II + i;
        hh[idx] = (__bf16)((float)hh[idx] * sc + off);
    }
}

// ---------------- final resample / gather: compact bf16 x -> full f32 out ----------------
__global__ __launch_bounds__(128) void gather_kernel(const __bf16* __restrict__ x,
                                                     const int* __restrict__ counts,
                                                     const int* __restrict__ vpos,
                                                     float* __restrict__ out)
{
    int m = blockIdx.x;
    int b = m >> 11;
    int t = m & (SS - 1);
    int A = counts[2 * b], Vn = counts[2 * b + 1];
    int d = threadIdx.x * 4;
    f4_t o = {0.f, 0.f, 0.f, 0.f};
    if (t < A && Vn > 0) {
        int Vs = Vn;
        int base = A / Vs, rem = A % Vs;
        int nb = Vs - rem;
        int split = nb * base;
        int bb = base > 1 ? base : 1;
        int j = (t < split) ? (t / bb) : (nb + (t - split) / (base + 1));
        if (j > Vs - 1) j = Vs - 1;
        int src = vpos[b * 256 + j];
        bf4_t bv = *reinterpret_cast<const bf4_t*>(&x[((size_t)b * WW + src) * DD + d]);
#pragma unroll
        for (int q = 0; q < 4; ++q) o[q] = (float)bv[q];
    }
    *reinterpret_cast<f4_t*>(&out[(size_t)m * DD + d]) = o;
}

// ---------------- launch ----------------
extern "C" void kernel_launch(void* const* d_in, const int* in_sizes, int n_in,
                              void* d_out, int out_size, void* d_ws, size_t ws_size,
                              hipStream_t stream)
{
    const int*   text  = (const int*)d_in[0];
    const int*   audio = (const int*)d_in[1];
    const float* table = (const float*)d_in[3];
    const float* freq  = (const float*)d_in[4];
    const float* dw_w  = (const float*)d_in[5];
    const float* dw_b  = (const float*)d_in[6];
    const float* ln_g  = (const float*)d_in[7];
    const float* ln_b  = (const float*)d_in[8];
    const float* w1    = (const float*)d_in[9];
    const float* b1    = (const float*)d_in[10];
    const float* grn_g = (const float*)d_in[11];
    const float* grn_b = (const float*)d_in[12];
    const float* w2    = (const float*)d_in[13];
    const float* b2    = (const float*)d_in[14];

    char* ws = (char*)d_ws;
    __bf16* x      = (__bf16*)(ws + 0);                // MC*DD*2   = 5 MB
    __bf16* hn     = (__bf16*)(ws + 6291456);          // 5 MB
    __bf16* hh     = (__bf16*)(ws + 12582912);         // MC*II*2   = 10 MB
    __bf16* wt1    = (__bf16*)(ws + 25165824);         // 4 MB
    __bf16* wt2    = (__bf16*)(ws + 29360128);         // 4 MB
    float*  keepf  = (float*)(ws + 33554432);          // MC*4 = 20 KB
    int*    counts = (int*)(ws + 33685504);            // 128 B
    int*    vpos   = (int*)(ws + 33685632);            // 16*256*4 = 16 KB
    int*    gflag  = (int*)(ws + 33947648);            // 16 B
    float*  out    = (float*)d_out;

    transpose_fused_kernel<<<4096, 256, 0, stream>>>(w1, w2, wt1, wt2);
    grn_flag_kernel<<<LL, 256, 0, stream>>>(grn_g, grn_b, gflag);
    embed_kernel<<<dim3(WW, BB), 128, 0, stream>>>(text, table, freq, x, keepf);
    counts_kernel<<<BB, 256, 0, stream>>>(keepf, audio, counts, vpos);

    for (int l = 0; l < LL; ++l) {
        conv_ln_kernel<<<dim3(WW / CT, BB), 256, 0, stream>>>(x, dw_w + l * DD * 7, dw_b + l * DD,
                                                              ln_g + l * DD, ln_b + l * DD, hn);
        gemm_kernel<0><<<(MC / 64) << 3, 256, 0, stream>>>(
            hn, wt1 + (size_t)l * DD * II, DD, II, 3, b1 + l * II, hh, nullptr, nullptr);
        grn_fused_kernel<<<BB, 1024, 0, stream>>>(hh, grn_g, grn_b, gflag, l);
        gemm_kernel<1><<<(MC / 64) << 2, 256, 0, stream>>>(
            hh, wt2 + (size_t)l * II * DD, II, DD, 2, b2 + l * DD, x, x, keepf);
    }

    gather_kernel<<<BB * SS, 128, 0, stream>>>(x, counts, vpos, out);
}

// Round 10
// 341.492 us; speedup vs baseline: 2.4444x; 1.0236x over previous
//
#include <hip/hip_runtime.h>
#include <hip/hip_bf16.h>

#define BB 16
#define TTc 256
#define SS 2048
#define WW 320         // compact tokens per batch (256 real + boundary/const rows)
#define MC (BB * WW)   // 5120 = 80 * 64
#define DD 512
#define II 1024
#define LL 4
#define MAXPOSc 4096
#define CT 16          // tokens per conv block

typedef __bf16 bf8_t __attribute__((ext_vector_type(8)));
typedef __bf16 bf4_t __attribute__((ext_vector_type(4)));
typedef float  f4_t  __attribute__((ext_vector_type(4)));

__device__ __forceinline__ void async_ld16(const __bf16* g, __bf16* lds)
{
    __builtin_amdgcn_global_load_lds(
        (const __attribute__((address_space(1))) void*)g,
        (__attribute__((address_space(3))) void*)lds,
        16, 0, 0);
}

// tanh-approx GELU: 0.5 v (1 + tanh(0.7978845608 (v + 0.044715 v^3)))
__device__ __forceinline__ float gelu_f(float v)
{
    float u = 0.7978845608f * v * (1.0f + 0.044715f * v * v);
    float e = __expf(2.0f * u);
    float t = 1.0f - 2.0f * __builtin_amdgcn_rcpf(e + 1.0f);
    return 0.5f * v * (1.0f + t);
}

// ---------------- fused prep: weight transposes + embed + counts (independent roles) ----
// blocks 0..2047    : w1 transpose tiles (R=512,C=1024)
// blocks 2048..4095 : w2 transpose tiles (R=1024,C=512)
// blocks 4096..5375 : embed, 4 tokens per block (1280 = 16 batches * 80)
// blocks 5376..5391 : counts/compaction per batch (keep recomputed from text)
__global__ __launch_bounds__(256) void prep_kernel(const float* __restrict__ w1,
                                                   const float* __restrict__ w2,
                                                   __bf16* __restrict__ o1,
                                                   __bf16* __restrict__ o2,
                                                   const int* __restrict__ text,
                                                   const float* __restrict__ table,
                                                   const float* __restrict__ freq,
                                                   __bf16* __restrict__ x,
                                                   float* __restrict__ keepf,
                                                   const int* __restrict__ audio,
                                                   int* __restrict__ counts,
                                                   int* __restrict__ vpos)
{
    __shared__ float ld[32][33];
    __shared__ int sc[256];
    int blk = blockIdx.x;
    int tid = threadIdx.x;

    if (blk < 4096) {                                   // ---- weight transpose ----
        const float* in;
        __bf16* out;
        int R, C, t;
        if (blk < 2048) { in = w1; out = o1; R = DD; C = II; t = blk; }
        else            { in = w2; out = o2; R = II; C = DD; t = blk - 2048; }
        int tpl = (R / 32) * (C / 32);                  // 512 tiles per layer
        int l = t / tpl; t -= l * tpl;
        int tr = t / (C / 32), tc = t % (C / 32);
        long base = (long)l * R * C;
        int ty = tid >> 5, tx = tid & 31;
#pragma unroll
        for (int i = 0; i < 4; ++i) {
            int r = tr * 32 + ty + i * 8;
            ld[ty + i * 8][tx] = in[base + (long)r * C + tc * 32 + tx];
        }
        __syncthreads();
#pragma unroll
        for (int i = 0; i < 4; ++i) {
            int c = tc * 32 + ty + i * 8;
            out[base + (long)c * R + tr * 32 + tx] = (__bf16)ld[tx][ty + i * 8];
        }
    } else if (blk < 5376) {                            // ---- embed (4 tokens/block) ----
        int e = blk - 4096;
        int b = e / 80;
        int t0 = (e % 80) * 4;
#pragma unroll
        for (int it = 0; it < 2; ++it) {
            int idx = it * 256 + tid;
            int t = t0 + (idx >> 7);
            int d4 = idx & 127;
            int tp = (t < TTc) ? (text[b * TTc + t] + 1) : 0;
            int m = b * WW + t;
            if (d4 == 0) keepf[m] = (tp != 0) ? 1.f : 0.f;
            int d = d4 * 4;
            bf4_t o;
            o[0] = (__bf16)0.f; o[1] = (__bf16)0.f; o[2] = (__bf16)0.f; o[3] = (__bf16)0.f;
            if (tp != 0) {
                f4_t ev = *reinterpret_cast<const f4_t*>(&table[(size_t)tp * DD + d]);
                f4_t fv = *reinterpret_cast<const f4_t*>(&freq[(size_t)t * DD + d]);
#pragma unroll
                for (int q = 0; q < 4; ++q) o[q] = (__bf16)(ev[q] + fv[q]);
            }
            *reinterpret_cast<bf4_t*>(&x[(size_t)m * DD + d]) = o;
        }
    } else {                                            // ---- counts / compaction ----
        int b = blk - 5376;
        int k = (text[b * TTc + tid] + 1) != 0;         // tid < 256
        sc[tid] = k;
        __syncthreads();
        for (int off = 1; off < 256; off <<= 1) {
            int v = sc[tid];
            int add = (tid >= off) ? sc[tid - off] : 0;
            __syncthreads();
            sc[tid] = v + add;
            __syncthreads();
        }
        int incl = sc[tid];
        int Vn = sc[255];
        if (k) vpos[b * 256 + (incl - 1)] = tid;
        int ac = 0;
#pragma unroll
        for (int j = 0; j < 8; ++j) ac += (audio[b * SS + tid * 8 + j] != 0);
        __syncthreads();
        sc[tid] = ac;
        __syncthreads();
        for (int off = 128; off > 0; off >>= 1) {
            if (tid < off) sc[tid] += sc[tid + off];
            __syncthreads();
        }
        if (tid == 0) { counts[2 * b] = sc[0]; counts[2 * b + 1] = Vn; }
    }
}

// ---------------- depthwise conv(7) + layernorm: compact bf16 x -> bf16 hn ----------------
__global__ __launch_bounds__(256) void conv_ln_kernel(const __bf16* __restrict__ x,
                                                      const float* __restrict__ w,
                                                      const float* __restrict__ wb,
                                                      const float* __restrict__ g,
                                                      const float* __restrict__ bta,
                                                      __bf16* __restrict__ hn)
{
    __shared__ float xs[CT + 6][DD];   // 44 KB
    int b = blockIdx.y;
    int t0 = blockIdx.x * CT;
    int tid = threadIdx.x;
    const __bf16* xb = x + (size_t)b * WW * DD;
#pragma unroll
    for (int it = 0; it < (CT + 6) * (DD / 4) / 256; ++it) {
        int i = it * 256 + tid;
        int ri = i >> 7;               // DD/4 = 128
        int c4 = i & 127;
        int tr = t0 - 3 + ri;
        f4_t v = {0.f, 0.f, 0.f, 0.f};
        if (tr >= 0 && tr < WW) {
            bf4_t bv = *reinterpret_cast<const bf4_t*>(&xb[(size_t)tr * DD + c4 * 4]);
#pragma unroll
            for (int q = 0; q < 4; ++q) v[q] = (float)bv[q];
        }
        *reinterpret_cast<f4_t*>(&xs[ri][c4 * 4]) = v;
    }
    __syncthreads();
    int tt = tid >> 4;                 // token within tile 0..15
    int lg = tid & 15;
    float hv[32];
    float s = 0.f, s2 = 0.f;
#pragma unroll
    for (int j = 0; j < 8; ++j) {
        int c = lg * 4 + j * 64;
        float a0 = wb[c], a1 = wb[c + 1], a2 = wb[c + 2], a3 = wb[c + 3];
#pragma unroll
        for (int k = 0; k < 7; ++k) {
            f4_t xv = *reinterpret_cast<const f4_t*>(&xs[tt + k][c]);
            a0 += xv[0] * w[(c + 0) * 7 + k];
            a1 += xv[1] * w[(c + 1) * 7 + k];
            a2 += xv[2] * w[(c + 2) * 7 + k];
            a3 += xv[3] * w[(c + 3) * 7 + k];
        }
        hv[j * 4 + 0] = a0; hv[j * 4 + 1] = a1; hv[j * 4 + 2] = a2; hv[j * 4 + 3] = a3;
        s += a0 + a1 + a2 + a3;
        s2 += a0 * a0 + a1 * a1 + a2 * a2 + a3 * a3;
    }
#pragma unroll
    for (int off = 8; off > 0; off >>= 1) {
        s  += __shfl_down(s, off, 16);
        s2 += __shfl_down(s2, off, 16);
    }
    s  = __shfl(s, 0, 16);
    s2 = __shfl(s2, 0, 16);
    float mu = s / DD;
    float rstd = rsqrtf(s2 / DD - mu * mu + 1e-6f);
    __bf16* hr = hn + ((size_t)b * WW + t0 + tt) * DD;
#pragma unroll
    for (int j = 0; j < 8; ++j) {
        int c = lg * 4 + j * 64;
        bf4_t o;
#pragma unroll
        for (int q = 0; q < 4; ++q)
            o[q] = (__bf16)((hv[j * 4 + q] - mu) * rstd * g[c + q] + bta[c + q]);
        *reinterpret_cast<bf4_t*>(&hr[c]) = o;
    }
}

// ---------------- bf16 MFMA GEMM: C[M,N] = A[M,K] x Wt[N,K]^T ----------------
// 64x128 tile, BK=32, R3-proven staging (global_load_lds width=16, unpadded
// tiles) + LDS-transpose epilogue. Grid = mtiles << nlog.
// EPI 0: hh_bf16 = gelu(acc + bias)                      (GEMM1)
// EPI 1: x_bf16  = (acc + bias + res_bf16) * keep[m]     (GEMM2, in-place residual)
template <int EPI>
__global__ __launch_bounds__(256) void gemm_kernel(const __bf16* __restrict__ A,
                                                   const __bf16* __restrict__ Wt,
                                                   int K, int N, int nlog,
                                                   const float* __restrict__ bias,
                                                   __bf16* __restrict__ outb,
                                                   const __bf16* __restrict__ res,
                                                   const float* __restrict__ keep)
{
    __shared__ float smem[4224];               // 16.9 KB arena
    __bf16* As = (__bf16*)smem;                // 64x32 bf16 = 4 KB
    __bf16* Bs = As + 64 * 32;                 // 128x32 bf16 = 8 KB
    float*  cs = smem;                         // epilogue 32x132 f32

    int tid = threadIdx.x;
    int lane = tid & 63, wid = tid >> 6;

    int idx = blockIdx.x;
    int n_t = idx & ((1 << nlog) - 1);
    int m_t = idx >> nlog;
    int n0 = n_t * 128, m0 = m_t * 64;

    f4_t acc[2][4];
#pragma unroll
    for (int i = 0; i < 2; ++i)
#pragma unroll
        for (int j = 0; j < 4; ++j) { f4_t z = {0.f, 0.f, 0.f, 0.f}; acc[i][j] = z; }

    const int wm = (wid >> 1) * 32, wn = (wid & 1) * 64;
    int fr = lane & 15, quad = lane >> 4;

    int r4 = lane >> 2;
    int scol = (lane & 3) * 8;
    const __bf16* ag = &A[(size_t)(m0 + wid * 16 + r4) * K + scol];
    const __bf16* bg = &Wt[(size_t)(n0 + wid * 32 + r4) * K + scol];
    __bf16* al = &As[(wid * 16) * 32];
    __bf16* bl0 = &Bs[(wid * 32) * 32];
    __bf16* bl1 = &Bs[(wid * 32 + 16) * 32];

    for (int k0 = 0; k0 < K; k0 += 32) {
        async_ld16(ag, al);
        async_ld16(bg, bl0);
        async_ld16(bg + (size_t)16 * K, bl1);
        ag += 32; bg += 32;
        __syncthreads();
        bf8_t af[2], bfr[4];
#pragma unroll
        for (int mi = 0; mi < 2; ++mi)
            af[mi] = *reinterpret_cast<const bf8_t*>(&As[(wm + mi * 16 + fr) * 32 + quad * 8]);
#pragma unroll
        for (int ni = 0; ni < 4; ++ni)
            bfr[ni] = *reinterpret_cast<const bf8_t*>(&Bs[(wn + ni * 16 + fr) * 32 + quad * 8]);
#pragma unroll
        for (int mi = 0; mi < 2; ++mi)
#pragma unroll
            for (int ni = 0; ni < 4; ++ni)
                acc[mi][ni] = __builtin_amdgcn_mfma_f32_16x16x32_bf16(af[mi], bfr[ni], acc[mi][ni], 0, 0, 0);
        __syncthreads();
    }

    // ---- epilogue: LDS transpose, 2 chunks of 32 rows x 128 cols ----
    const int lrbase = (wm >> 5) * 16 + quad * 4;
#pragma unroll
    for (int mi = 0; mi < 2; ++mi) {
        __syncthreads();
#pragma unroll
        for (int ni = 0; ni < 4; ++ni) {
            int col = wn + ni * 16 + fr;
#pragma unroll
            for (int r = 0; r < 4; ++r)
                cs[(lrbase + r) * 132 + col] = acc[mi][ni][r];
        }
        __syncthreads();
#pragma unroll
        for (int p = 0; p < 4; ++p) {
            int lr = p * 8 + (tid >> 5);
            int c = (tid & 31) * 4;
            int gr = m0 + ((lr < 16) ? (mi * 16 + lr) : (32 + mi * 16 + (lr - 16)));
            f4_t v = *reinterpret_cast<const f4_t*>(&cs[lr * 132 + c]);
            f4_t bv = *reinterpret_cast<const f4_t*>(&bias[n0 + c]);
            v = v + bv;
            bf4_t o;
            if (EPI == 0) {
#pragma unroll
                for (int q = 0; q < 4; ++q) o[q] = (__bf16)gelu_f(v[q]);
            } else {
                bf4_t rv = *reinterpret_cast<const bf4_t*>(&res[(size_t)gr * N + n0 + c]);
                float kp = keep[gr];
#pragma unroll
                for (int q = 0; q < 4; ++q) o[q] = (__bf16)((v[q] + (float)rv[q]) * kp);
            }
            *reinterpret_cast<bf4_t*>(&outb[(size_t)gr * N + n0 + c]) = o;
        }
    }
}

// ---------------- fused GRN (inline flag check; exact constant-row correction) ----
// One block per batch: inline any(gg!=0||gb!=0) gate, per-channel seq-sum
// (+ (S-WW)*const^2), block-reduce for channel-mean of sqrt, apply in-place.
__global__ __launch_bounds__(1024) void grn_fused_kernel(__bf16* __restrict__ hh,
                                                         const float* __restrict__ gg,
                                                         const float* __restrict__ gb,
                                                         int l)
{
    int b = blockIdx.x;
    int i = threadIdx.x;               // channel 0..1023
    float gv = gg[l * II + i];
    float bv = gb[l * II + i];
    __shared__ int any_s;
    if (i == 0) any_s = 0;
    __syncthreads();
    if (gv != 0.f || bv != 0.f) atomicOr(&any_s, 1);
    __syncthreads();
    if (!any_s) return;

    float acc = 0.f;
    for (int s = 0; s < WW; ++s) {
        float v = (float)hh[((size_t)b * WW + s) * II + i];
        acc += v * v;
    }
    float c = (float)hh[((size_t)b * WW + WW - 1) * II + i];
    acc += (float)(SS - WW) * c * c;
    float gx = sqrtf(acc);
    __shared__ float red[1024];
    red[i] = gx;
    __syncthreads();
    for (int off = 512; off > 0; off >>= 1) {
        if (i < off) red[i] += red[i + off];
        __syncthreads();
    }
    float mean = red[0] / II;
    float nx = gx / (mean + 1e-6f);
    float sc = 1.f + gv * nx;
    for (int s = 0; s < WW; ++s) {
        size_t idx = ((size_t)b * WW + s) * II + i;
        hh[idx] = (__bf16)((float)hh[idx] * sc + bv);
    }
}

// ---------------- final resample / gather: compact bf16 x -> full f32 out ----------------
// 8 tokens per block (256 threads, 32-thread group per token).
__global__ __launch_bounds__(256) void gather_kernel(const __bf16* __restrict__ x,
                                                     const int* __restrict__ counts,
                                                     const int* __restrict__ vpos,
                                                     float* __restrict__ out)
{
    int m = blockIdx.x * 8 + (threadIdx.x >> 5);
    int b = m >> 11;
    int t = m & (SS - 1);
    int A = counts[2 * b], Vn = counts[2 * b + 1];
    int lane32 = threadIdx.x & 31;
    int src = -1;
    if (t < A && Vn > 0) {
        int Vs = Vn;
        int base = A / Vs, rem = A % Vs;
        int nb = Vs - rem;
        int split = nb * base;
        int bb = base > 1 ? base : 1;
        int j = (t < split) ? (t / bb) : (nb + (t - split) / (base + 1));
        if (j > Vs - 1) j = Vs - 1;
        src = vpos[b * 256 + j];
    }
#pragma unroll
    for (int dd = 0; dd < 4; ++dd) {
        int d = (lane32 + dd * 32) * 4;
        f4_t o = {0.f, 0.f, 0.f, 0.f};
        if (src >= 0) {
            bf4_t bv = *reinterpret_cast<const bf4_t*>(&x[((size_t)b * WW + src) * DD + d]);
#pragma unroll
            for (int q = 0; q < 4; ++q) o[q] = (float)bv[q];
        }
        *reinterpret_cast<f4_t*>(&out[(size_t)m * DD + d]) = o;
    }
}

// ---------------- launch ----------------
extern "C" void kernel_launch(void* const* d_in, const int* in_sizes, int n_in,
                              void* d_out, int out_size, void* d_ws, size_t ws_size,
                              hipStream_t stream)
{
    const int*   text  = (const int*)d_in[0];
    const int*   audio = (const int*)d_in[1];
    const float* table = (const float*)d_in[3];
    const float* freq  = (const float*)d_in[4];
    const float* dw_w  = (const float*)d_in[5];
    const float* dw_b  = (const float*)d_in[6];
    const float* ln_g  = (const float*)d_in[7];
    const float* ln_b  = (const float*)d_in[8];
    const float* w1    = (const float*)d_in[9];
    const float* b1    = (const float*)d_in[10];
    const float* grn_g = (const float*)d_in[11];
    const float* grn_b = (const float*)d_in[12];
    const float* w2    = (const float*)d_in[13];
    const float* b2    = (const float*)d_in[14];

    char* ws = (char*)d_ws;
    __bf16* x      = (__bf16*)(ws + 0);                // MC*DD*2   = 5 MB
    __bf16* hn     = (__bf16*)(ws + 6291456);          // 5 MB
    __bf16* hh     = (__bf16*)(ws + 12582912);         // MC*II*2   = 10 MB
    __bf16* wt1    = (__bf16*)(ws + 25165824);         // 4 MB
    __bf16* wt2    = (__bf16*)(ws + 29360128);         // 4 MB
    float*  keepf  = (float*)(ws + 33554432);          // MC*4 = 20 KB
    int*    counts = (int*)(ws + 33685504);            // 128 B
    int*    vpos   = (int*)(ws + 33685632);            // 16*256*4 = 16 KB
    float*  out    = (float*)d_out;

    prep_kernel<<<5392, 256, 0, stream>>>(w1, w2, wt1, wt2, text, table, freq,
                                          x, keepf, audio, counts, vpos);

    for (int l = 0; l < LL; ++l) {
        conv_ln_kernel<<<dim3(WW / CT, BB), 256, 0, stream>>>(x, dw_w + l * DD * 7, dw_b + l * DD,
                                                              ln_g + l * DD, ln_b + l * DD, hn);
        gemm_kernel<0><<<(MC / 64) << 3, 256, 0, stream>>>(
            hn, wt1 + (size_t)l * DD * II, DD, II, 3, b1 + l * II, hh, nullptr, nullptr);
        grn_fused_kernel<<<BB, 1024, 0, stream>>>(hh, grn_g, grn_b, l);
        gemm_kernel<1><<<(MC / 64) << 2, 256, 0, stream>>>(
            hh, wt2 + (size_t)l * II * DD, II, DD, 2, b2 + l * DD, x, x, keepf);
    }

    gather_kernel<<<BB * SS / 8, 256, 0, stream>>>(x, counts, vpos, out);
}